// Round 1
// baseline (1431.040 us; speedup 1.0000x reference)
//
#include <hip/hip_runtime.h>
#include <hip/hip_bf16.h>
#include <stdint.h>

#define NNODES 100000
#define NEDGES 1600000
#define C2 128
#define EFEAT 32
#define BN_EPS 1e-5f
#define CH 32
#define SCAN_B ((NNODES + 255) / 256)  // 391 blocks for the CSR offset scan

typedef __hip_bfloat16 bf16;

__device__ __forceinline__ float bflo(uint32_t u) { return __uint_as_float(u << 16); }
__device__ __forceinline__ float bfhi(uint32_t u) { return __uint_as_float(u & 0xffff0000u); }
__device__ __forceinline__ float sigm(float x) { return 1.0f / (1.0f + __expf(-x)); }
__device__ __forceinline__ float softp(float x) { return fmaxf(x, 0.0f) + log1pf(__expf(-fabsf(x))); }

struct TB {};  // tensors are bf16
struct TF {};  // tensors are fp32

template <class T> struct LD;
template <> struct LD<TB> {
    static __device__ __forceinline__ float ld(const void* p, size_t i) {
        return __bfloat162float(((const bf16*)p)[i]);
    }
    static __device__ __forceinline__ float2 ld2(const void* p, size_t i) {
        const uint32_t u = *(const uint32_t*)((const bf16*)p + i);
        return make_float2(bflo(u), bfhi(u));
    }
    static __device__ __forceinline__ float4 ld4(const void* p, size_t i) {
        const uint2 v = *(const uint2*)((const bf16*)p + i);
        return make_float4(bflo(v.x), bfhi(v.x), bflo(v.y), bfhi(v.y));
    }
    static __device__ __forceinline__ void st2(void* p, size_t i, float a, float b) {
        union { bf16 h[2]; uint32_t u; } pk;
        pk.h[0] = __float2bfloat16(a);
        pk.h[1] = __float2bfloat16(b);
        *(uint32_t*)((bf16*)p + i) = pk.u;
    }
};
template <> struct LD<TF> {
    static __device__ __forceinline__ float ld(const void* p, size_t i) {
        return ((const float*)p)[i];
    }
    static __device__ __forceinline__ float2 ld2(const void* p, size_t i) {
        return *(const float2*)((const float*)p + i);
    }
    static __device__ __forceinline__ float4 ld4(const void* p, size_t i) {
        return *(const float4*)((const float*)p + i);
    }
    static __device__ __forceinline__ void st2(void* p, size_t i, float a, float b) {
        *(float2*)((float*)p + i) = make_float2(a, b);
    }
};

// K0: detect dtype. fp32 data read as packed bf16 has huge low-half values.
__global__ void k_detect(const uint32_t* __restrict__ nodeb, int* __restrict__ flag) {
    __shared__ int sfp;
    if (threadIdx.x == 0) sfp = 0;
    __syncthreads();
    const float v = fabsf(bflo(nodeb[threadIdx.x]));
    if (v > 1e10f) sfp = 1;
    __syncthreads();
    if (threadIdx.x == 0) *flag = sfp;
}

// ---------------- CSR build: hist -> scan -> fill -------------------------
__global__ __launch_bounds__(256) void k_hist(const int* __restrict__ dst,
                                              int* __restrict__ cnt) {
    for (int e = blockIdx.x * 256 + threadIdx.x; e < NEDGES; e += gridDim.x * 256)
        atomicAdd(&cnt[dst[e]], 1);
}

__global__ __launch_bounds__(256) void k_scan1(const int* __restrict__ cnt,
                                               int* __restrict__ bsum) {
    __shared__ int red[256];
    const int t = threadIdx.x;
    const int i = blockIdx.x * 256 + t;
    red[t] = (i < NNODES) ? cnt[i] : 0;
    __syncthreads();
    for (int s = 128; s > 0; s >>= 1) {
        if (t < s) red[t] += red[t + s];
        __syncthreads();
    }
    if (t == 0) bsum[blockIdx.x] = red[0];
}

// single block, 512 threads: exclusive scan of SCAN_B (=391) block sums
__global__ void k_scan2(int* __restrict__ bsum) {
    __shared__ int sh[512];
    const int t = threadIdx.x;
    const int v0 = (t < SCAN_B) ? bsum[t] : 0;
    sh[t] = v0;
    __syncthreads();
    for (int ofs = 1; ofs < 512; ofs <<= 1) {
        const int v = (t >= ofs) ? sh[t - ofs] : 0;
        __syncthreads();
        sh[t] += v;
        __syncthreads();
    }
    if (t < SCAN_B) bsum[t] = sh[t] - v0;  // exclusive
}

__global__ __launch_bounds__(256) void k_scan3(const int* __restrict__ cnt,
                                               const int* __restrict__ bsum,
                                               int* __restrict__ off,
                                               int* __restrict__ cur) {
    __shared__ int sh[256];
    const int t = threadIdx.x;
    const int i = blockIdx.x * 256 + t;
    const int orig = (i < NNODES) ? cnt[i] : 0;
    sh[t] = orig;
    __syncthreads();
    for (int ofs = 1; ofs < 256; ofs <<= 1) {
        const int v = (t >= ofs) ? sh[t - ofs] : 0;
        __syncthreads();
        sh[t] += v;
        __syncthreads();
    }
    const int excl = sh[t] - orig + bsum[blockIdx.x];
    if (i < NNODES) { off[i] = excl; cur[i] = excl; }
    if (i == NNODES) off[NNODES] = excl;  // == NEDGES
}

__global__ __launch_bounds__(256) void k_fill(const int* __restrict__ dst,
                                              int* __restrict__ cur,
                                              int* __restrict__ eid) {
    for (int e = blockIdx.x * 256 + threadIdx.x; e < NEDGES; e += gridDim.x * 256) {
        const int p = atomicAdd(&cur[dst[e]], 1);
        eid[p] = e;
    }
}

// ---------------- K1: per-node tables -----------------------------------
template <class T>
__device__ __forceinline__ void tables_body(
    const void* node, const void* Wsrc, const void* bsrc,
    const void* Wdst, const void* bdst, bf16* tsrc, bf16* tdst, float* x)
{
    const int t = threadIdx.x;
    const int col = t & 127;
    const void* W = (t < 128) ? Wsrc : Wdst;
    float w[64];
#pragma unroll
    for (int k = 0; k < 64; ++k) w[k] = LD<T>::ld(W, k * C2 + col);
    const float b = (t < 128) ? LD<T>::ld(bsrc, col) : LD<T>::ld(bdst, col);
    bf16* tab = (t < 128) ? tsrc : tdst;
    const int pos = (col < 64) ? (2 * col) : (2 * col - 127);
    for (int base = blockIdx.x * 4; base < NNODES; base += gridDim.x * 4) {
        x[t] = LD<T>::ld(node, (size_t)base * 64 + t);
        __syncthreads();
        float a0 = b, a1 = b, a2 = b, a3 = b;
#pragma unroll
        for (int k = 0; k < 64; ++k) {
            const float wv = w[k];
            a0 = fmaf(x[k], wv, a0);
            a1 = fmaf(x[64 + k], wv, a1);
            a2 = fmaf(x[128 + k], wv, a2);
            a3 = fmaf(x[192 + k], wv, a3);
        }
        __syncthreads();
        tab[(size_t)(base + 0) * C2 + pos] = __float2bfloat16(a0);
        tab[(size_t)(base + 1) * C2 + pos] = __float2bfloat16(a1);
        tab[(size_t)(base + 2) * C2 + pos] = __float2bfloat16(a2);
        tab[(size_t)(base + 3) * C2 + pos] = __float2bfloat16(a3);
    }
}

__global__ __launch_bounds__(256, 4) void k_tables(
    const void* node, const void* Wsrc, const void* bsrc,
    const void* Wdst, const void* bdst, bf16* tsrc, bf16* tdst, const int* flag)
{
    __shared__ float x[256];
    if (*flag) tables_body<TF>(node, Wsrc, bsrc, Wdst, bdst, tsrc, tdst, x);
    else       tables_body<TB>(node, Wsrc, bsrc, Wdst, bdst, tsrc, tdst, x);
}

// ---------------- K2: edge stats ----------------------------------------
template <class T>
__device__ __forceinline__ void edge_stats_body(
    const void* ef, const int* src, const int* dst, const void* We, const void* be,
    const uint32_t* tsrc, const uint32_t* tdst, float* mstats,
    float* efb, int* sidx, int* didx, float* red)
{
    const int t = threadIdx.x;
    const int c = t & 63;
    const int eg = t >> 6;
    float w0[EFEAT], w1[EFEAT];
#pragma unroll
    for (int k = 0; k < EFEAT; ++k) {
        w0[k] = LD<T>::ld(We, k * C2 + c);
        w1[k] = LD<T>::ld(We, k * C2 + c + 64);
    }
    const float be0 = LD<T>::ld(be, c), be1 = LD<T>::ld(be, c + 64);
    float s0 = 0.f, q0 = 0.f, s1 = 0.f, q1 = 0.f;
    for (int chunk = blockIdx.x * CH; chunk < NEDGES; chunk += gridDim.x * CH) {
        ((float4*)efb)[t] = LD<T>::ld4(ef, (size_t)chunk * EFEAT + 4 * t);
        if (t < CH) sidx[t] = src[chunk + t];
        else if (t < 2 * CH) didx[t - CH] = dst[chunk + t - CH];
        __syncthreads();
        for (int e0 = 0; e0 < CH; e0 += 4) {
            const int e = e0 + eg;
            const int s = sidx[e], d = didx[e];
            float el0 = be0, el1 = be1;
            const float4* efv = (const float4*)(efb + e * EFEAT);
#pragma unroll
            for (int k4 = 0; k4 < EFEAT / 4; ++k4) {
                const float4 f = efv[k4];
                el0 = fmaf(f.x, w0[4 * k4 + 0], el0); el1 = fmaf(f.x, w1[4 * k4 + 0], el1);
                el0 = fmaf(f.y, w0[4 * k4 + 1], el0); el1 = fmaf(f.y, w1[4 * k4 + 1], el1);
                el0 = fmaf(f.z, w0[4 * k4 + 2], el0); el1 = fmaf(f.z, w1[4 * k4 + 2], el1);
                el0 = fmaf(f.w, w0[4 * k4 + 3], el0); el1 = fmaf(f.w, w1[4 * k4 + 3], el1);
            }
            const uint32_t us = tsrc[(size_t)s * 64 + c];
            const uint32_t ud = tdst[(size_t)d * 64 + c];
            const float m0 = el0 + bflo(us) + bflo(ud);
            const float m1 = el1 + bfhi(us) + bfhi(ud);
            s0 += m0; q0 += m0 * m0;
            s1 += m1; q1 += m1 * m1;
        }
        __syncthreads();
    }
    ((float4*)red)[t] = make_float4(s0, q0, s1, q1);
    __syncthreads();
    if (t < 64) {
        float a0 = 0.f, a1 = 0.f, a2 = 0.f, a3 = 0.f;
        for (int g = 0; g < 4; ++g) {
            const float4 r = ((const float4*)red)[g * 64 + t];
            a0 += r.x; a1 += r.y; a2 += r.z; a3 += r.w;
        }
        atomicAdd(&mstats[t], a0);
        atomicAdd(&mstats[C2 + t], a1);
        atomicAdd(&mstats[t + 64], a2);
        atomicAdd(&mstats[C2 + t + 64], a3);
    }
}

__global__ __launch_bounds__(256, 4) void k_edge_stats(
    const void* ef, const int* src, const int* dst, const void* We, const void* be,
    const uint32_t* tsrc, const uint32_t* tdst, float* mstats, const int* flag)
{
    __shared__ float efb[CH * EFEAT];
    __shared__ int sidx[CH], didx[CH];
    __shared__ float red[1024];
    if (*flag) edge_stats_body<TF>(ef, src, dst, We, be, tsrc, tdst, mstats, efb, sidx, didx, red);
    else       edge_stats_body<TB>(ef, src, dst, We, be, tsrc, tdst, mstats, efb, sidx, didx, red);
}

// ---------------- K3: finalize m-BN -------------------------------------
template <class T>
__device__ __forceinline__ void fin_m_body(const float* mstats, const void* gamma,
                                           const void* beta, float* mss)
{
    const int c = threadIdx.x;  // 128
    const float inv = 1.0f / (float)NEDGES;
    const float mean = mstats[c] * inv;
    const float var = fmaxf(mstats[C2 + c] * inv - mean * mean, 0.0f);
    const float sc = LD<T>::ld(gamma, c) * rsqrtf(var + BN_EPS);
    mss[c] = sc;
    mss[C2 + c] = LD<T>::ld(beta, c) - mean * sc;
}

__global__ void k_fin_m(const float* mstats, const void* gamma, const void* beta,
                        float* mss, const int* flag)
{
    if (*flag) fin_m_body<TF>(mstats, gamma, beta, mss);
    else       fin_m_body<TB>(mstats, gamma, beta, mss);
}

// ---------------- K4': CSR gather-aggregate ------------------------------
// One wave (64 lanes = 64 output channels) owns one dst node: tdst row
// loaded once per node (was once per edge), gate accumulated in registers
// (was 64 global f32 atomics per edge), one coalesced 256B store per node.
// eid/src/ef addresses are wave-uniform -> readfirstlane for scalar-path
// broadcast loads. Node-BN stats fused (replaces k_node_stats).
template <class T>
__device__ __forceinline__ void aggregate_body(
    const void* ef, const int* src, const void* We, const void* be,
    const uint32_t* tsrc, const uint32_t* tdst, const float* mss,
    const int* off, const int* eid, float* hacc, float* nstats, float* red)
{
    const int t = threadIdx.x;
    const int c = t & 63;
    const int g = t >> 6;  // wave id within block; one wave = one node
    float w0[EFEAT], w1[EFEAT];
#pragma unroll
    for (int k = 0; k < EFEAT; ++k) {
        w0[k] = LD<T>::ld(We, k * C2 + c);
        w1[k] = LD<T>::ld(We, k * C2 + c + 64);
    }
    const float be0 = LD<T>::ld(be, c), be1 = LD<T>::ld(be, c + 64);
    const float sc0 = mss[c], sh0 = mss[C2 + c];
    const float sc1 = mss[c + 64], sh1 = mss[C2 + c + 64];
    float s = 0.f, q = 0.f;
    for (int d0 = blockIdx.x * 4; d0 < NNODES; d0 += gridDim.x * 4) {
        const int d = d0 + g;  // wave-uniform
        const uint32_t ud = tdst[(size_t)d * 64 + c];
        const float hd0 = bflo(ud), hd1 = bfhi(ud);
        const int beg = __builtin_amdgcn_readfirstlane(off[d]);
        const int end = __builtin_amdgcn_readfirstlane(off[d + 1]);
        float acc = 0.f;
        int e = (beg < end) ? __builtin_amdgcn_readfirstlane(eid[beg]) : 0;
        int sn = (beg < end) ? __builtin_amdgcn_readfirstlane(src[e]) : 0;
        for (int p = beg; p < end; ++p) {
            const int ecur = e, scur = sn;
            const uint32_t us = tsrc[(size_t)scur * 64 + c];
            if (p + 1 < end) {
                e = __builtin_amdgcn_readfirstlane(eid[p + 1]);
                sn = __builtin_amdgcn_readfirstlane(src[e]);
            }
            float el0 = be0, el1 = be1;
#pragma unroll
            for (int k4 = 0; k4 < EFEAT / 4; ++k4) {
                const float4 f = LD<T>::ld4(ef, (size_t)ecur * EFEAT + 4 * k4);
                el0 = fmaf(f.x, w0[4 * k4 + 0], el0); el1 = fmaf(f.x, w1[4 * k4 + 0], el1);
                el0 = fmaf(f.y, w0[4 * k4 + 1], el0); el1 = fmaf(f.y, w1[4 * k4 + 1], el1);
                el0 = fmaf(f.z, w0[4 * k4 + 2], el0); el1 = fmaf(f.z, w1[4 * k4 + 2], el1);
                el0 = fmaf(f.w, w0[4 * k4 + 3], el0); el1 = fmaf(f.w, w1[4 * k4 + 3], el1);
            }
            const float m0 = el0 + bflo(us) + hd0;
            const float m1 = el1 + bfhi(us) + hd1;
            acc += sigm(fmaf(m0, sc0, sh0)) * softp(fmaf(m1, sc1, sh1));
        }
        hacc[(size_t)d * 64 + c] = acc;
        s += acc; q += acc * acc;
    }
    red[t] = s; red[256 + t] = q;
    __syncthreads();
    if (t < 64) {
        float a = 0.f, b = 0.f;
        for (int gg = 0; gg < 4; ++gg) { a += red[gg * 64 + t]; b += red[256 + gg * 64 + t]; }
        atomicAdd(&nstats[t], a);
        atomicAdd(&nstats[64 + t], b);
    }
}

__global__ __launch_bounds__(256, 4) void k_aggregate(
    const void* ef, const int* src, const void* We, const void* be,
    const uint32_t* tsrc, const uint32_t* tdst, const float* mss,
    const int* off, const int* eid, float* hacc, float* nstats, const int* flag)
{
    __shared__ float red[512];
    if (*flag) aggregate_body<TF>(ef, src, We, be, tsrc, tdst, mss, off, eid, hacc, nstats, red);
    else       aggregate_body<TB>(ef, src, We, be, tsrc, tdst, mss, off, eid, hacc, nstats, red);
}

// ---------------- K6: finalize n-BN -------------------------------------
template <class T>
__device__ __forceinline__ void fin_n_body(const float* nstats, const void* gamma,
                                           const void* beta, float* nss)
{
    const int c = threadIdx.x;  // 64
    const float inv = 1.0f / (float)NNODES;
    const float mean = nstats[c] * inv;
    const float var = fmaxf(nstats[64 + c] * inv - mean * mean, 0.0f);
    const float sc = LD<T>::ld(gamma, c) * rsqrtf(var + BN_EPS);
    nss[c] = sc;
    nss[64 + c] = LD<T>::ld(beta, c) - mean * sc;
}

__global__ void k_fin_n(const float* nstats, const void* gamma, const void* beta,
                        float* nss, const int* flag)
{
    if (*flag) fin_n_body<TF>(nstats, gamma, beta, nss);
    else       fin_n_body<TB>(nstats, gamma, beta, nss);
}

// ---------------- K7: output --------------------------------------------
template <class T>
__device__ __forceinline__ void out_body(const void* node, const float* hacc,
                                         const float* nss, void* out)
{
    const int t = threadIdx.x;
    const int64_t npairs = (int64_t)NNODES * 32;
    int64_t i = (int64_t)blockIdx.x * 256 + t;
    const int c0 = (int)((i * 2) & 63);  // stride is a multiple of 64 elements
    const float sc0 = nss[c0], sh0 = nss[64 + c0];
    const float sc1 = nss[c0 + 1], sh1 = nss[64 + c0 + 1];
    const float2* hp = (const float2*)hacc;
    const int64_t stride = (int64_t)gridDim.x * 256;
    for (; i < npairs; i += stride) {
        const float2 nv = LD<T>::ld2(node, (size_t)(2 * i));
        const float2 h = hp[i];
        const float v0 = softp(nv.x + fmaf(h.x, sc0, sh0));
        const float v1 = softp(nv.y + fmaf(h.y, sc1, sh1));
        LD<T>::st2(out, (size_t)(2 * i), v0, v1);
    }
}

__global__ __launch_bounds__(256) void k_out(const void* node, const float* hacc,
                                             const float* nss, void* out, const int* flag)
{
    if (*flag) out_body<TF>(node, hacc, nss, out);
    else       out_body<TB>(node, hacc, nss, out);
}

extern "C" void kernel_launch(void* const* d_in, const int* in_sizes, int n_in,
                              void* d_out, int out_size, void* d_ws, size_t ws_size,
                              hipStream_t stream)
{
    const void* node = d_in[0];
    const void* ef   = d_in[1];
    const void* Wsrc = d_in[2];
    const void* bsrc = d_in[3];
    const void* Wdst = d_in[4];
    const void* bdst = d_in[5];
    const void* We   = d_in[6];
    const void* be   = d_in[7];
    const void* gm   = d_in[8];
    const void* bm   = d_in[9];
    const void* gn   = d_in[10];
    const void* bn   = d_in[11];
    const int* src   = (const int*)d_in[12];
    const int* dst   = (const int*)d_in[13];

    // ws: hacc(N*64 f32) | mstats(256) | nstats(128) | mss(256) | nss(128) |
    //     flag(4 ints) | tsrc | tdst | cnt(N) | off(N+1) | cur(N) | bsum(512) | eid(E)
    float* hacc   = (float*)d_ws;
    float* mstats = hacc + (size_t)NNODES * 64;
    float* nstats = mstats + 256;
    float* mss    = nstats + 128;
    float* nss    = mss + 256;
    int* flag     = (int*)(nss + 128);
    bf16* tsrc    = (bf16*)(flag + 4);
    bf16* tdst    = tsrc + (size_t)NNODES * C2;
    int* cnt      = (int*)(tdst + (size_t)NNODES * C2);
    int* off      = cnt + NNODES;
    int* cur      = off + NNODES + 1;
    int* bsum     = cur + NNODES;
    int* eid      = bsum + 512;

    // hacc no longer needs zeroing (fully written by k_aggregate)
    hipMemsetAsync(mstats, 0, 384 * sizeof(float), stream);
    hipMemsetAsync(cnt, 0, NNODES * sizeof(int), stream);
    k_detect<<<1, 256, 0, stream>>>((const uint32_t*)node, flag);
    // CSR build (cheap; enables atomic-free aggregation)
    k_hist<<<2048, 256, 0, stream>>>(dst, cnt);
    k_scan1<<<SCAN_B, 256, 0, stream>>>(cnt, bsum);
    k_scan2<<<1, 512, 0, stream>>>(bsum);
    k_scan3<<<SCAN_B, 256, 0, stream>>>(cnt, bsum, off, cur);
    k_fill<<<2048, 256, 0, stream>>>(dst, cur, eid);
    k_tables<<<512, 256, 0, stream>>>(node, Wsrc, bsrc, Wdst, bdst, tsrc, tdst, flag);
    k_edge_stats<<<2048, 256, 0, stream>>>(ef, src, dst, We, be,
                                           (const uint32_t*)tsrc, (const uint32_t*)tdst,
                                           mstats, flag);
    k_fin_m<<<1, 128, 0, stream>>>(mstats, gm, bm, mss, flag);
    k_aggregate<<<2048, 256, 0, stream>>>(ef, src, We, be,
                                          (const uint32_t*)tsrc, (const uint32_t*)tdst,
                                          mss, off, eid, hacc, nstats, flag);
    k_fin_n<<<1, 64, 0, stream>>>(nstats, gn, bn, nss, flag);
    k_out<<<1024, 256, 0, stream>>>(node, hacc, nss, d_out, flag);
}

// Round 2
// 1258.083 us; speedup vs baseline: 1.1375x; 1.1375x over previous
//
#include <hip/hip_runtime.h>
#include <hip/hip_bf16.h>
#include <stdint.h>

#define NNODES 100000
#define NEDGES 1600000
#define C2 128
#define EFEAT 32
#define BN_EPS 1e-5f
#define CH 32
#define SCAN_B ((NNODES + 255) / 256)  // 391 blocks for the CSR offset scan

typedef __hip_bfloat16 bf16;

__device__ __forceinline__ float bflo(uint32_t u) { return __uint_as_float(u << 16); }
__device__ __forceinline__ float bfhi(uint32_t u) { return __uint_as_float(u & 0xffff0000u); }
__device__ __forceinline__ float sigm(float x) { return 1.0f / (1.0f + __expf(-x)); }
// softplus via hw v_log_f32: z = exp(-|x|) in (0,1], log(1+z) well-conditioned
__device__ __forceinline__ float softp(float x) { return fmaxf(x, 0.0f) + __logf(1.0f + __expf(-fabsf(x))); }

struct TB {};  // tensors are bf16
struct TF {};  // tensors are fp32

template <class T> struct LD;
template <> struct LD<TB> {
    static __device__ __forceinline__ float ld(const void* p, size_t i) {
        return __bfloat162float(((const bf16*)p)[i]);
    }
    static __device__ __forceinline__ float2 ld2(const void* p, size_t i) {
        const uint32_t u = *(const uint32_t*)((const bf16*)p + i);
        return make_float2(bflo(u), bfhi(u));
    }
    static __device__ __forceinline__ float4 ld4(const void* p, size_t i) {
        const uint2 v = *(const uint2*)((const bf16*)p + i);
        return make_float4(bflo(v.x), bfhi(v.x), bflo(v.y), bfhi(v.y));
    }
    static __device__ __forceinline__ void st2(void* p, size_t i, float a, float b) {
        union { bf16 h[2]; uint32_t u; } pk;
        pk.h[0] = __float2bfloat16(a);
        pk.h[1] = __float2bfloat16(b);
        *(uint32_t*)((bf16*)p + i) = pk.u;
    }
};
template <> struct LD<TF> {
    static __device__ __forceinline__ float ld(const void* p, size_t i) {
        return ((const float*)p)[i];
    }
    static __device__ __forceinline__ float2 ld2(const void* p, size_t i) {
        return *(const float2*)((const float*)p + i);
    }
    static __device__ __forceinline__ float4 ld4(const void* p, size_t i) {
        return *(const float4*)((const float*)p + i);
    }
    static __device__ __forceinline__ void st2(void* p, size_t i, float a, float b) {
        *(float2*)((float*)p + i) = make_float2(a, b);
    }
};

// K0: detect dtype. fp32 data read as packed bf16 has huge low-half values.
__global__ void k_detect(const uint32_t* __restrict__ nodeb, int* __restrict__ flag) {
    __shared__ int sfp;
    if (threadIdx.x == 0) sfp = 0;
    __syncthreads();
    const float v = fabsf(bflo(nodeb[threadIdx.x]));
    if (v > 1e10f) sfp = 1;
    __syncthreads();
    if (threadIdx.x == 0) *flag = sfp;
}

// ---------------- CSR build: hist -> scan -> fill -------------------------
__global__ __launch_bounds__(256) void k_hist(const int* __restrict__ dst,
                                              int* __restrict__ cnt) {
    for (int e = blockIdx.x * 256 + threadIdx.x; e < NEDGES; e += gridDim.x * 256)
        atomicAdd(&cnt[dst[e]], 1);
}

__global__ __launch_bounds__(256) void k_scan1(const int* __restrict__ cnt,
                                               int* __restrict__ bsum) {
    __shared__ int red[256];
    const int t = threadIdx.x;
    const int i = blockIdx.x * 256 + t;
    red[t] = (i < NNODES) ? cnt[i] : 0;
    __syncthreads();
    for (int s = 128; s > 0; s >>= 1) {
        if (t < s) red[t] += red[t + s];
        __syncthreads();
    }
    if (t == 0) bsum[blockIdx.x] = red[0];
}

// single block, 512 threads: exclusive scan of SCAN_B (=391) block sums
__global__ void k_scan2(int* __restrict__ bsum) {
    __shared__ int sh[512];
    const int t = threadIdx.x;
    const int v0 = (t < SCAN_B) ? bsum[t] : 0;
    sh[t] = v0;
    __syncthreads();
    for (int ofs = 1; ofs < 512; ofs <<= 1) {
        const int v = (t >= ofs) ? sh[t - ofs] : 0;
        __syncthreads();
        sh[t] += v;
        __syncthreads();
    }
    if (t < SCAN_B) bsum[t] = sh[t] - v0;  // exclusive
}

__global__ __launch_bounds__(256) void k_scan3(const int* __restrict__ cnt,
                                               const int* __restrict__ bsum,
                                               int* __restrict__ off,
                                               int* __restrict__ cur) {
    __shared__ int sh[256];
    const int t = threadIdx.x;
    const int i = blockIdx.x * 256 + t;
    const int orig = (i < NNODES) ? cnt[i] : 0;
    sh[t] = orig;
    __syncthreads();
    for (int ofs = 1; ofs < 256; ofs <<= 1) {
        const int v = (t >= ofs) ? sh[t - ofs] : 0;
        __syncthreads();
        sh[t] += v;
        __syncthreads();
    }
    const int excl = sh[t] - orig + bsum[blockIdx.x];
    if (i < NNODES) { off[i] = excl; cur[i] = excl; }
    if (i == NNODES) off[NNODES] = excl;  // == NEDGES
}

__global__ __launch_bounds__(256) void k_fill(const int* __restrict__ dst,
                                              int* __restrict__ cur,
                                              int* __restrict__ eid) {
    for (int e = blockIdx.x * 256 + threadIdx.x; e < NEDGES; e += gridDim.x * 256) {
        const int p = atomicAdd(&cur[dst[e]], 1);
        eid[p] = e;
    }
}

// ---------------- K1: per-node tables -----------------------------------
template <class T>
__device__ __forceinline__ void tables_body(
    const void* node, const void* Wsrc, const void* bsrc,
    const void* Wdst, const void* bdst, bf16* tsrc, bf16* tdst, float* x)
{
    const int t = threadIdx.x;
    const int col = t & 127;
    const void* W = (t < 128) ? Wsrc : Wdst;
    float w[64];
#pragma unroll
    for (int k = 0; k < 64; ++k) w[k] = LD<T>::ld(W, k * C2 + col);
    const float b = (t < 128) ? LD<T>::ld(bsrc, col) : LD<T>::ld(bdst, col);
    bf16* tab = (t < 128) ? tsrc : tdst;
    const int pos = (col < 64) ? (2 * col) : (2 * col - 127);
    for (int base = blockIdx.x * 4; base < NNODES; base += gridDim.x * 4) {
        x[t] = LD<T>::ld(node, (size_t)base * 64 + t);
        __syncthreads();
        float a0 = b, a1 = b, a2 = b, a3 = b;
#pragma unroll
        for (int k = 0; k < 64; ++k) {
            const float wv = w[k];
            a0 = fmaf(x[k], wv, a0);
            a1 = fmaf(x[64 + k], wv, a1);
            a2 = fmaf(x[128 + k], wv, a2);
            a3 = fmaf(x[192 + k], wv, a3);
        }
        __syncthreads();
        tab[(size_t)(base + 0) * C2 + pos] = __float2bfloat16(a0);
        tab[(size_t)(base + 1) * C2 + pos] = __float2bfloat16(a1);
        tab[(size_t)(base + 2) * C2 + pos] = __float2bfloat16(a2);
        tab[(size_t)(base + 3) * C2 + pos] = __float2bfloat16(a3);
    }
}

__global__ __launch_bounds__(256, 4) void k_tables(
    const void* node, const void* Wsrc, const void* bsrc,
    const void* Wdst, const void* bdst, bf16* tsrc, bf16* tdst, const int* flag)
{
    __shared__ float x[256];
    if (*flag) tables_body<TF>(node, Wsrc, bsrc, Wdst, bdst, tsrc, tdst, x);
    else       tables_body<TB>(node, Wsrc, bsrc, Wdst, bdst, tsrc, tdst, x);
}

// ---------------- K2: edge stats (unchanged control) ---------------------
template <class T>
__device__ __forceinline__ void edge_stats_body(
    const void* ef, const int* src, const int* dst, const void* We, const void* be,
    const uint32_t* tsrc, const uint32_t* tdst, float* mstats,
    float* efb, int* sidx, int* didx, float* red)
{
    const int t = threadIdx.x;
    const int c = t & 63;
    const int eg = t >> 6;
    float w0[EFEAT], w1[EFEAT];
#pragma unroll
    for (int k = 0; k < EFEAT; ++k) {
        w0[k] = LD<T>::ld(We, k * C2 + c);
        w1[k] = LD<T>::ld(We, k * C2 + c + 64);
    }
    const float be0 = LD<T>::ld(be, c), be1 = LD<T>::ld(be, c + 64);
    float s0 = 0.f, q0 = 0.f, s1 = 0.f, q1 = 0.f;
    for (int chunk = blockIdx.x * CH; chunk < NEDGES; chunk += gridDim.x * CH) {
        ((float4*)efb)[t] = LD<T>::ld4(ef, (size_t)chunk * EFEAT + 4 * t);
        if (t < CH) sidx[t] = src[chunk + t];
        else if (t < 2 * CH) didx[t - CH] = dst[chunk + t - CH];
        __syncthreads();
        for (int e0 = 0; e0 < CH; e0 += 4) {
            const int e = e0 + eg;
            const int s = sidx[e], d = didx[e];
            float el0 = be0, el1 = be1;
            const float4* efv = (const float4*)(efb + e * EFEAT);
#pragma unroll
            for (int k4 = 0; k4 < EFEAT / 4; ++k4) {
                const float4 f = efv[k4];
                el0 = fmaf(f.x, w0[4 * k4 + 0], el0); el1 = fmaf(f.x, w1[4 * k4 + 0], el1);
                el0 = fmaf(f.y, w0[4 * k4 + 1], el0); el1 = fmaf(f.y, w1[4 * k4 + 1], el1);
                el0 = fmaf(f.z, w0[4 * k4 + 2], el0); el1 = fmaf(f.z, w1[4 * k4 + 2], el1);
                el0 = fmaf(f.w, w0[4 * k4 + 3], el0); el1 = fmaf(f.w, w1[4 * k4 + 3], el1);
            }
            const uint32_t us = tsrc[(size_t)s * 64 + c];
            const uint32_t ud = tdst[(size_t)d * 64 + c];
            const float m0 = el0 + bflo(us) + bflo(ud);
            const float m1 = el1 + bfhi(us) + bfhi(ud);
            s0 += m0; q0 += m0 * m0;
            s1 += m1; q1 += m1 * m1;
        }
        __syncthreads();
    }
    ((float4*)red)[t] = make_float4(s0, q0, s1, q1);
    __syncthreads();
    if (t < 64) {
        float a0 = 0.f, a1 = 0.f, a2 = 0.f, a3 = 0.f;
        for (int g = 0; g < 4; ++g) {
            const float4 r = ((const float4*)red)[g * 64 + t];
            a0 += r.x; a1 += r.y; a2 += r.z; a3 += r.w;
        }
        atomicAdd(&mstats[t], a0);
        atomicAdd(&mstats[C2 + t], a1);
        atomicAdd(&mstats[t + 64], a2);
        atomicAdd(&mstats[C2 + t + 64], a3);
    }
}

__global__ __launch_bounds__(256, 4) void k_edge_stats(
    const void* ef, const int* src, const int* dst, const void* We, const void* be,
    const uint32_t* tsrc, const uint32_t* tdst, float* mstats, const int* flag)
{
    __shared__ float efb[CH * EFEAT];
    __shared__ int sidx[CH], didx[CH];
    __shared__ float red[1024];
    if (*flag) edge_stats_body<TF>(ef, src, dst, We, be, tsrc, tdst, mstats, efb, sidx, didx, red);
    else       edge_stats_body<TB>(ef, src, dst, We, be, tsrc, tdst, mstats, efb, sidx, didx, red);
}

// ---------------- K3: finalize m-BN -------------------------------------
template <class T>
__device__ __forceinline__ void fin_m_body(const float* mstats, const void* gamma,
                                           const void* beta, float* mss)
{
    const int c = threadIdx.x;  // 128
    const float inv = 1.0f / (float)NEDGES;
    const float mean = mstats[c] * inv;
    const float var = fmaxf(mstats[C2 + c] * inv - mean * mean, 0.0f);
    const float sc = LD<T>::ld(gamma, c) * rsqrtf(var + BN_EPS);
    mss[c] = sc;
    mss[C2 + c] = LD<T>::ld(beta, c) - mean * sc;
}

__global__ void k_fin_m(const float* mstats, const void* gamma, const void* beta,
                        float* mss, const int* flag)
{
    if (*flag) fin_m_body<TF>(mstats, gamma, beta, mss);
    else       fin_m_body<TB>(mstats, gamma, beta, mss);
}

// ---------------- K4': CSR gather-aggregate, v2 ---------------------------
// R1 post-mortem: v1 compiled to VGPR_Count=64 -> the 64 We weights were
// rematerialized/spilled and re-read EVERY edge (VALUBusy 88%, 690us).
// v2: (a) weights as 16 NAMED float4 locals (nothing for the spiller to
// sink), (b) batched edge-index loads: 64 lanes load up to 64 eid/src at
// once, per-edge broadcast via __shfl -> no dependent scalar-load chain.
#define EFMA(W0v, W1v, fv)                                        \
    el0 = fmaf((fv).x, (W0v).x, el0); el1 = fmaf((fv).x, (W1v).x, el1); \
    el0 = fmaf((fv).y, (W0v).y, el0); el1 = fmaf((fv).y, (W1v).y, el1); \
    el0 = fmaf((fv).z, (W0v).z, el0); el1 = fmaf((fv).z, (W1v).z, el1); \
    el0 = fmaf((fv).w, (W0v).w, el0); el1 = fmaf((fv).w, (W1v).w, el1);

#define LDW(j)                                                                       \
    const float4 W0##j = make_float4(LD<T>::ld(We, (4 * j + 0) * C2 + c),            \
                                     LD<T>::ld(We, (4 * j + 1) * C2 + c),            \
                                     LD<T>::ld(We, (4 * j + 2) * C2 + c),            \
                                     LD<T>::ld(We, (4 * j + 3) * C2 + c));           \
    const float4 W1##j = make_float4(LD<T>::ld(We, (4 * j + 0) * C2 + c + 64),       \
                                     LD<T>::ld(We, (4 * j + 1) * C2 + c + 64),       \
                                     LD<T>::ld(We, (4 * j + 2) * C2 + c + 64),       \
                                     LD<T>::ld(We, (4 * j + 3) * C2 + c + 64));

template <class T>
__device__ __forceinline__ void aggregate_body(
    const void* ef, const int* src, const void* We, const void* be,
    const uint32_t* tsrc, const uint32_t* tdst, const float* mss,
    const int* off, const int* eid, float* hacc, float* nstats, float* red)
{
    const int t = threadIdx.x;
    const int c = t & 63;
    const int g = t >> 6;  // wave id within block; one wave = one node
    LDW(0) LDW(1) LDW(2) LDW(3) LDW(4) LDW(5) LDW(6) LDW(7)
    const float be0 = LD<T>::ld(be, c), be1 = LD<T>::ld(be, c + 64);
    const float sc0 = mss[c], sh0 = mss[C2 + c];
    const float sc1 = mss[c + 64], sh1 = mss[C2 + c + 64];
    float s = 0.f, q = 0.f;
    for (int d0 = blockIdx.x * 4; d0 < NNODES; d0 += gridDim.x * 4) {
        const int d = d0 + g;  // wave-uniform (NNODES % 4 == 0)
        const uint32_t ud = tdst[(size_t)d * 64 + c];
        const float hd0 = bflo(ud), hd1 = bfhi(ud);
        const int beg = __builtin_amdgcn_readfirstlane(off[d]);
        const int end = __builtin_amdgcn_readfirstlane(off[d + 1]);
        float acc = 0.f;
        for (int b = beg; b < end; b += 64) {
            const int nb = min(64, end - b);
            const int eb = (b + c < end) ? eid[b + c] : 0;
            const int sb = (b + c < end) ? src[eb] : 0;
            for (int i = 0; i < nb; ++i) {
                const int e = __shfl(eb, i, 64);
                const int sn = __shfl(sb, i, 64);
                const uint32_t us = tsrc[(size_t)sn * 64 + c];
                const size_t eb4 = (size_t)e * EFEAT;
                const float4 f0 = LD<T>::ld4(ef, eb4 + 0);
                const float4 f1 = LD<T>::ld4(ef, eb4 + 4);
                const float4 f2 = LD<T>::ld4(ef, eb4 + 8);
                const float4 f3 = LD<T>::ld4(ef, eb4 + 12);
                const float4 f4 = LD<T>::ld4(ef, eb4 + 16);
                const float4 f5 = LD<T>::ld4(ef, eb4 + 20);
                const float4 f6 = LD<T>::ld4(ef, eb4 + 24);
                const float4 f7 = LD<T>::ld4(ef, eb4 + 28);
                float el0 = be0, el1 = be1;
                EFMA(W00, W10, f0) EFMA(W01, W11, f1)
                EFMA(W02, W12, f2) EFMA(W03, W13, f3)
                EFMA(W04, W14, f4) EFMA(W05, W15, f5)
                EFMA(W06, W16, f6) EFMA(W07, W17, f7)
                const float m0 = el0 + bflo(us) + hd0;
                const float m1 = el1 + bfhi(us) + hd1;
                acc += sigm(fmaf(m0, sc0, sh0)) * softp(fmaf(m1, sc1, sh1));
            }
        }
        hacc[(size_t)d * 64 + c] = acc;
        s += acc; q += acc * acc;
    }
    red[t] = s; red[256 + t] = q;
    __syncthreads();
    if (t < 64) {
        float a = 0.f, b = 0.f;
        for (int gg = 0; gg < 4; ++gg) { a += red[gg * 64 + t]; b += red[256 + gg * 64 + t]; }
        atomicAdd(&nstats[t], a);
        atomicAdd(&nstats[64 + t], b);
    }
}

__global__ __launch_bounds__(256, 4) void k_aggregate(
    const void* ef, const int* src, const void* We, const void* be,
    const uint32_t* tsrc, const uint32_t* tdst, const float* mss,
    const int* off, const int* eid, float* hacc, float* nstats, const int* flag)
{
    __shared__ float red[512];
    if (*flag) aggregate_body<TF>(ef, src, We, be, tsrc, tdst, mss, off, eid, hacc, nstats, red);
    else       aggregate_body<TB>(ef, src, We, be, tsrc, tdst, mss, off, eid, hacc, nstats, red);
}

// ---------------- K6: finalize n-BN -------------------------------------
template <class T>
__device__ __forceinline__ void fin_n_body(const float* nstats, const void* gamma,
                                           const void* beta, float* nss)
{
    const int c = threadIdx.x;  // 64
    const float inv = 1.0f / (float)NNODES;
    const float mean = nstats[c] * inv;
    const float var = fmaxf(nstats[64 + c] * inv - mean * mean, 0.0f);
    const float sc = LD<T>::ld(gamma, c) * rsqrtf(var + BN_EPS);
    nss[c] = sc;
    nss[64 + c] = LD<T>::ld(beta, c) - mean * sc;
}

__global__ void k_fin_n(const float* nstats, const void* gamma, const void* beta,
                        float* nss, const int* flag)
{
    if (*flag) fin_n_body<TF>(nstats, gamma, beta, nss);
    else       fin_n_body<TB>(nstats, gamma, beta, nss);
}

// ---------------- K7: output --------------------------------------------
template <class T>
__device__ __forceinline__ void out_body(const void* node, const float* hacc,
                                         const float* nss, void* out)
{
    const int t = threadIdx.x;
    const int64_t npairs = (int64_t)NNODES * 32;
    int64_t i = (int64_t)blockIdx.x * 256 + t;
    const int c0 = (int)((i * 2) & 63);  // stride is a multiple of 64 elements
    const float sc0 = nss[c0], sh0 = nss[64 + c0];
    const float sc1 = nss[c0 + 1], sh1 = nss[64 + c0 + 1];
    const float2* hp = (const float2*)hacc;
    const int64_t stride = (int64_t)gridDim.x * 256;
    for (; i < npairs; i += stride) {
        const float2 nv = LD<T>::ld2(node, (size_t)(2 * i));
        const float2 h = hp[i];
        const float v0 = softp(nv.x + fmaf(h.x, sc0, sh0));
        const float v1 = softp(nv.y + fmaf(h.y, sc1, sh1));
        LD<T>::st2(out, (size_t)(2 * i), v0, v1);
    }
}

__global__ __launch_bounds__(256) void k_out(const void* node, const float* hacc,
                                             const float* nss, void* out, const int* flag)
{
    if (*flag) out_body<TF>(node, hacc, nss, out);
    else       out_body<TB>(node, hacc, nss, out);
}

extern "C" void kernel_launch(void* const* d_in, const int* in_sizes, int n_in,
                              void* d_out, int out_size, void* d_ws, size_t ws_size,
                              hipStream_t stream)
{
    const void* node = d_in[0];
    const void* ef   = d_in[1];
    const void* Wsrc = d_in[2];
    const void* bsrc = d_in[3];
    const void* Wdst = d_in[4];
    const void* bdst = d_in[5];
    const void* We   = d_in[6];
    const void* be   = d_in[7];
    const void* gm   = d_in[8];
    const void* bm   = d_in[9];
    const void* gn   = d_in[10];
    const void* bn   = d_in[11];
    const int* src   = (const int*)d_in[12];
    const int* dst   = (const int*)d_in[13];

    // ws: hacc(N*64 f32) | mstats(256) | nstats(128) | mss(256) | nss(128) |
    //     flag(4 ints) | tsrc | tdst | cnt(N) | off(N+1) | cur(N) | bsum(512) | eid(E)
    float* hacc   = (float*)d_ws;
    float* mstats = hacc + (size_t)NNODES * 64;
    float* nstats = mstats + 256;
    float* mss    = nstats + 128;
    float* nss    = mss + 256;
    int* flag     = (int*)(nss + 128);
    bf16* tsrc    = (bf16*)(flag + 4);
    bf16* tdst    = tsrc + (size_t)NNODES * C2;
    int* cnt      = (int*)(tdst + (size_t)NNODES * C2);
    int* off      = cnt + NNODES;
    int* cur      = off + NNODES + 1;
    int* bsum     = cur + NNODES;
    int* eid      = bsum + 512;

    hipMemsetAsync(mstats, 0, 384 * sizeof(float), stream);
    hipMemsetAsync(cnt, 0, NNODES * sizeof(int), stream);
    k_detect<<<1, 256, 0, stream>>>((const uint32_t*)node, flag);
    // CSR build (cheap; enables atomic-free aggregation)
    k_hist<<<2048, 256, 0, stream>>>(dst, cnt);
    k_scan1<<<SCAN_B, 256, 0, stream>>>(cnt, bsum);
    k_scan2<<<1, 512, 0, stream>>>(bsum);
    k_scan3<<<SCAN_B, 256, 0, stream>>>(cnt, bsum, off, cur);
    k_fill<<<2048, 256, 0, stream>>>(dst, cur, eid);
    k_tables<<<512, 256, 0, stream>>>(node, Wsrc, bsrc, Wdst, bdst, tsrc, tdst, flag);
    k_edge_stats<<<2048, 256, 0, stream>>>(ef, src, dst, We, be,
                                           (const uint32_t*)tsrc, (const uint32_t*)tdst,
                                           mstats, flag);
    k_fin_m<<<1, 128, 0, stream>>>(mstats, gm, bm, mss, flag);
    k_aggregate<<<2048, 256, 0, stream>>>(ef, src, We, be,
                                          (const uint32_t*)tsrc, (const uint32_t*)tdst,
                                          mss, off, eid, hacc, nstats, flag);
    k_fin_n<<<1, 64, 0, stream>>>(nstats, gn, bn, nss, flag);
    k_out<<<1024, 256, 0, stream>>>(node, hacc, nss, d_out, flag);
}

// Round 4
// 1208.567 us; speedup vs baseline: 1.1841x; 1.0410x over previous
//
#include <hip/hip_runtime.h>
#include <hip/hip_bf16.h>
#include <stdint.h>

#define NNODES 100000
#define NEDGES 1600000
#define C2 128
#define EFEAT 32
#define BN_EPS 1e-5f
#define SCAN_B ((NNODES + 255) / 256)  // 391 blocks for the CSR offset scan

typedef __hip_bfloat16 bf16;

__device__ __forceinline__ float bflo(uint32_t u) { return __uint_as_float(u << 16); }
__device__ __forceinline__ float bfhi(uint32_t u) { return __uint_as_float(u & 0xffff0000u); }
__device__ __forceinline__ float sigm(float x) { return 1.0f / (1.0f + __expf(-x)); }
// softplus via hw v_log_f32: z = exp(-|x|) in (0,1], log(1+z) well-conditioned
__device__ __forceinline__ float softp(float x) { return fmaxf(x, 0.0f) + __logf(1.0f + __expf(-fabsf(x))); }
__device__ __forceinline__ uint32_t pk2(float a, float b) {
    union { bf16 h[2]; uint32_t u; } pk;
    pk.h[0] = __float2bfloat16(a);
    pk.h[1] = __float2bfloat16(b);
    return pk.u;
}

struct TB {};  // tensors are bf16
struct TF {};  // tensors are fp32

template <class T> struct LD;
template <> struct LD<TB> {
    static __device__ __forceinline__ float ld(const void* p, size_t i) {
        return __bfloat162float(((const bf16*)p)[i]);
    }
    static __device__ __forceinline__ float2 ld2(const void* p, size_t i) {
        const uint32_t u = *(const uint32_t*)((const bf16*)p + i);
        return make_float2(bflo(u), bfhi(u));
    }
    static __device__ __forceinline__ void st2(void* p, size_t i, float a, float b) {
        *(uint32_t*)((bf16*)p + i) = pk2(a, b);
    }
    // one 32-feat edge row -> 4 uint4 of packed bf16 (verbatim copy)
    static __device__ __forceinline__ void ldrow(const void* p, size_t e, uint4* o) {
        const uint4* er = (const uint4*)p + e * 4;
        o[0] = er[0]; o[1] = er[1]; o[2] = er[2]; o[3] = er[3];
    }
};
template <> struct LD<TF> {
    static __device__ __forceinline__ float ld(const void* p, size_t i) {
        return ((const float*)p)[i];
    }
    static __device__ __forceinline__ float2 ld2(const void* p, size_t i) {
        return *(const float2*)((const float*)p + i);
    }
    static __device__ __forceinline__ void st2(void* p, size_t i, float a, float b) {
        *(float2*)((float*)p + i) = make_float2(a, b);
    }
    // one 32-feat fp32 edge row -> 4 uint4 of packed bf16
    static __device__ __forceinline__ void ldrow(const void* p, size_t e, uint4* o) {
        const float4* fr = (const float4*)p + e * 8;
#pragma unroll
        for (int j = 0; j < 4; ++j) {
            const float4 a = fr[2 * j], b = fr[2 * j + 1];
            o[j] = make_uint4(pk2(a.x, a.y), pk2(a.z, a.w), pk2(b.x, b.y), pk2(b.z, b.w));
        }
    }
};

// K0: detect dtype. fp32 data read as packed bf16 has huge low-half values.
__global__ void k_detect(const uint32_t* __restrict__ nodeb, int* __restrict__ flag) {
    __shared__ int sfp;
    if (threadIdx.x == 0) sfp = 0;
    __syncthreads();
    const float v = fabsf(bflo(nodeb[threadIdx.x]));
    if (v > 1e10f) sfp = 1;
    __syncthreads();
    if (threadIdx.x == 0) *flag = sfp;
}

// ---------------- CSR build: hist -> scan -> fill(+permute) ---------------
__global__ __launch_bounds__(256) void k_hist(const int* __restrict__ dst,
                                              int* __restrict__ cnt) {
    for (int e = blockIdx.x * 256 + threadIdx.x; e < NEDGES; e += gridDim.x * 256)
        atomicAdd(&cnt[dst[e]], 1);
}

__global__ __launch_bounds__(256) void k_scan1(const int* __restrict__ cnt,
                                               int* __restrict__ bsum) {
    __shared__ int red[256];
    const int t = threadIdx.x;
    const int i = blockIdx.x * 256 + t;
    red[t] = (i < NNODES) ? cnt[i] : 0;
    __syncthreads();
    for (int s = 128; s > 0; s >>= 1) {
        if (t < s) red[t] += red[t + s];
        __syncthreads();
    }
    if (t == 0) bsum[blockIdx.x] = red[0];
}

// single block, 512 threads: exclusive scan of SCAN_B (=391) block sums
__global__ void k_scan2(int* __restrict__ bsum) {
    __shared__ int sh[512];
    const int t = threadIdx.x;
    const int v0 = (t < SCAN_B) ? bsum[t] : 0;
    sh[t] = v0;
    __syncthreads();
    for (int ofs = 1; ofs < 512; ofs <<= 1) {
        const int v = (t >= ofs) ? sh[t - ofs] : 0;
        __syncthreads();
        sh[t] += v;
        __syncthreads();
    }
    if (t < SCAN_B) bsum[t] = sh[t] - v0;  // exclusive
}

__global__ __launch_bounds__(256) void k_scan3(const int* __restrict__ cnt,
                                               const int* __restrict__ bsum,
                                               int* __restrict__ off,
                                               int* __restrict__ cur) {
    __shared__ int sh[256];
    const int t = threadIdx.x;
    const int i = blockIdx.x * 256 + t;
    const int orig = (i < NNODES) ? cnt[i] : 0;
    sh[t] = orig;
    __syncthreads();
    for (int ofs = 1; ofs < 256; ofs <<= 1) {
        const int v = (t >= ofs) ? sh[t - ofs] : 0;
        __syncthreads();
        sh[t] += v;
        __syncthreads();
    }
    const int excl = sh[t] - orig + bsum[blockIdx.x];
    if (i < NNODES) { off[i] = excl; cur[i] = excl; }
    if (i == NNODES) off[NNODES] = excl;  // == NEDGES
}

// fill + fused permute: per edge e at CSR position p, record srcp[p]=src[e]
// and write the bf16 edge-feature row to efp[p]. Kills the separate permute
// pass and the eid buffer; ef is read exactly once in the whole pipeline.
template <class T>
__device__ __forceinline__ void fill_body(const int* __restrict__ dst,
                                          const int* __restrict__ src,
                                          const void* __restrict__ ef,
                                          int* __restrict__ cur,
                                          int* __restrict__ srcp,
                                          uint4* __restrict__ efp4)
{
    for (int e = blockIdx.x * 256 + threadIdx.x; e < NEDGES; e += gridDim.x * 256) {
        uint4 o[4];
        LD<T>::ldrow(ef, e, o);
        const int p = atomicAdd(&cur[dst[e]], 1);
        srcp[p] = src[e];
        uint4* w = efp4 + (size_t)p * 4;
        w[0] = o[0]; w[1] = o[1]; w[2] = o[2]; w[3] = o[3];
    }
}

__global__ __launch_bounds__(256) void k_fill(const int* __restrict__ dst,
                                              const int* __restrict__ src,
                                              const void* __restrict__ ef,
                                              int* __restrict__ cur,
                                              int* __restrict__ srcp,
                                              uint4* __restrict__ efp4,
                                              const int* __restrict__ flag)
{
    if (*flag) fill_body<TF>(dst, src, ef, cur, srcp, efp4);
    else       fill_body<TB>(dst, src, ef, cur, srcp, efp4);
}

// ---------------- K1: per-node tables -----------------------------------
template <class T>
__device__ __forceinline__ void tables_body(
    const void* node, const void* Wsrc, const void* bsrc,
    const void* Wdst, const void* bdst, bf16* tsrc, bf16* tdst, float* x)
{
    const int t = threadIdx.x;
    const int col = t & 127;
    const void* W = (t < 128) ? Wsrc : Wdst;
    float w[64];
#pragma unroll
    for (int k = 0; k < 64; ++k) w[k] = LD<T>::ld(W, k * C2 + col);
    const float b = (t < 128) ? LD<T>::ld(bsrc, col) : LD<T>::ld(bdst, col);
    bf16* tab = (t < 128) ? tsrc : tdst;
    const int pos = (col < 64) ? (2 * col) : (2 * col - 127);
    for (int base = blockIdx.x * 4; base < NNODES; base += gridDim.x * 4) {
        x[t] = LD<T>::ld(node, (size_t)base * 64 + t);
        __syncthreads();
        float a0 = b, a1 = b, a2 = b, a3 = b;
#pragma unroll
        for (int k = 0; k < 64; ++k) {
            const float wv = w[k];
            a0 = fmaf(x[k], wv, a0);
            a1 = fmaf(x[64 + k], wv, a1);
            a2 = fmaf(x[128 + k], wv, a2);
            a3 = fmaf(x[192 + k], wv, a3);
        }
        __syncthreads();
        tab[(size_t)(base + 0) * C2 + pos] = __float2bfloat16(a0);
        tab[(size_t)(base + 1) * C2 + pos] = __float2bfloat16(a1);
        tab[(size_t)(base + 2) * C2 + pos] = __float2bfloat16(a2);
        tab[(size_t)(base + 3) * C2 + pos] = __float2bfloat16(a3);
    }
}

__global__ __launch_bounds__(256, 4) void k_tables(
    const void* node, const void* Wsrc, const void* bsrc,
    const void* Wdst, const void* bdst, bf16* tsrc, bf16* tdst, const int* flag)
{
    __shared__ float x[256];
    if (*flag) tables_body<TF>(node, Wsrc, bsrc, Wdst, bdst, tsrc, tdst, x);
    else       tables_body<TB>(node, Wsrc, bsrc, Wdst, bdst, tsrc, tdst, x);
}

// ---------------- K3: finalize m-BN -------------------------------------
template <class T>
__device__ __forceinline__ void fin_m_body(const float* mstats, const void* gamma,
                                           const void* beta, float* mss)
{
    const int c = threadIdx.x;  // 128
    const float inv = 1.0f / (float)NEDGES;
    const float mean = mstats[c] * inv;
    const float var = fmaxf(mstats[C2 + c] * inv - mean * mean, 0.0f);
    const float sc = LD<T>::ld(gamma, c) * rsqrtf(var + BN_EPS);
    mss[c] = sc;
    mss[C2 + c] = LD<T>::ld(beta, c) - mean * sc;
}

__global__ void k_fin_m(const float* mstats, const void* gamma, const void* beta,
                        float* mss, const int* flag)
{
    if (*flag) fin_m_body<TF>(mstats, gamma, beta, mss);
    else       fin_m_body<TB>(mstats, gamma, beta, mss);
}

// ---------------- unified CSR edge pass (STATS / aggregate) ---------------
// One wave = one dst node (64 lanes = 64 channel-pairs). tdst row read once
// per node (sequential in d); efp is the CSR-permuted bf16 edge stream
// (sequential); tsrc is the only gather. 2-deep pipeline: next edge's efp
// row + tsrc row prefetched under the current edge's 64 FMAs.
// STATS=true  -> accumulate m-BN sum/sumsq into mstats (replaces k_edge_stats)
// STATS=false -> gate + hacc write + n-BN sums into nstats (k_aggregate)
// R2 post-mortem: VGPR stuck at 64 because the hacc store could alias
// We/mss/tsrc (no restrict) -> weight hoisting illegal -> remat per edge.
// Fix: __restrict__ on every pointer + waves_per_eu(4,4) (128-VGPR budget).
#define EFMAD(ua, ub, W0v, W1v) {                                   \
    const float fx = bflo(ua), fy = bfhi(ua);                       \
    const float fz = bflo(ub), fw = bfhi(ub);                       \
    el0 = fmaf(fx, (W0v).x, el0); el1 = fmaf(fx, (W1v).x, el1);     \
    el0 = fmaf(fy, (W0v).y, el0); el1 = fmaf(fy, (W1v).y, el1);     \
    el0 = fmaf(fz, (W0v).z, el0); el1 = fmaf(fz, (W1v).z, el1);     \
    el0 = fmaf(fw, (W0v).w, el0); el1 = fmaf(fw, (W1v).w, el1); }

#define LDW(j)                                                                       \
    const float4 W0##j = make_float4(LD<T>::ld(We, (4 * j + 0) * C2 + c),            \
                                     LD<T>::ld(We, (4 * j + 1) * C2 + c),            \
                                     LD<T>::ld(We, (4 * j + 2) * C2 + c),            \
                                     LD<T>::ld(We, (4 * j + 3) * C2 + c));           \
    const float4 W1##j = make_float4(LD<T>::ld(We, (4 * j + 0) * C2 + c + 64),       \
                                     LD<T>::ld(We, (4 * j + 1) * C2 + c + 64),       \
                                     LD<T>::ld(We, (4 * j + 2) * C2 + c + 64),       \
                                     LD<T>::ld(We, (4 * j + 3) * C2 + c + 64));

template <class T, bool STATS>
__device__ __forceinline__ void edge_pass_body(
    const uint4* __restrict__ efp4, const int* __restrict__ srcp,
    const void* __restrict__ We, const void* __restrict__ be,
    const uint32_t* __restrict__ tsrc, const uint32_t* __restrict__ tdst,
    const float* __restrict__ mss, const int* __restrict__ off,
    float* __restrict__ hacc, float* __restrict__ ost, float* __restrict__ red)
{
    const int t = threadIdx.x;
    const int c = t & 63;
    const int g = t >> 6;  // wave id within block; one wave = one node
    LDW(0) LDW(1) LDW(2) LDW(3) LDW(4) LDW(5) LDW(6) LDW(7)
    const float be0 = LD<T>::ld(be, c), be1 = LD<T>::ld(be, c + 64);
    float sc0 = 0.f, sh0 = 0.f, sc1 = 0.f, sh1 = 0.f;
    if constexpr (!STATS) {
        sc0 = mss[c];      sh0 = mss[C2 + c];
        sc1 = mss[c + 64]; sh1 = mss[C2 + c + 64];
    }
    float s0 = 0.f, q0 = 0.f, s1 = 0.f, q1 = 0.f;
    for (int d0 = blockIdx.x * 4; d0 < NNODES; d0 += gridDim.x * 4) {
        const int d = d0 + g;  // wave-uniform (NNODES % 4 == 0)
        const uint32_t ud = tdst[(size_t)d * 64 + c];
        const float hd0 = bflo(ud), hd1 = bfhi(ud);
        const int beg = __builtin_amdgcn_readfirstlane(off[d]);
        const int end = __builtin_amdgcn_readfirstlane(off[d + 1]);
        float acc = 0.f;
        for (int b = beg; b < end; b += 64) {
            const int nb = min(64, end - b);
            const int sb = (b + c < end) ? srcp[b + c] : 0;
            uint4 n0, n1, n2, n3;
            {
                const uint4* rp = efp4 + (size_t)b * 4;
                n0 = rp[0]; n1 = rp[1]; n2 = rp[2]; n3 = rp[3];
            }
            uint32_t usn = tsrc[(size_t)__shfl(sb, 0, 64) * 64 + c];
            for (int i = 0; i < nb; ++i) {
                const uint4 r0 = n0, r1 = n1, r2 = n2, r3 = n3;
                const uint32_t us = usn;
                if (i + 1 < nb) {  // wave-uniform branch
                    const uint4* rp = efp4 + (size_t)(b + i + 1) * 4;
                    n0 = rp[0]; n1 = rp[1]; n2 = rp[2]; n3 = rp[3];
                    usn = tsrc[(size_t)__shfl(sb, i + 1, 64) * 64 + c];
                }
                float el0 = be0, el1 = be1;
                EFMAD(r0.x, r0.y, W00, W10) EFMAD(r0.z, r0.w, W01, W11)
                EFMAD(r1.x, r1.y, W02, W12) EFMAD(r1.z, r1.w, W03, W13)
                EFMAD(r2.x, r2.y, W04, W14) EFMAD(r2.z, r2.w, W05, W15)
                EFMAD(r3.x, r3.y, W06, W16) EFMAD(r3.z, r3.w, W07, W17)
                const float m0 = el0 + bflo(us) + hd0;
                const float m1 = el1 + bfhi(us) + hd1;
                if constexpr (STATS) {
                    s0 += m0; q0 += m0 * m0;
                    s1 += m1; q1 += m1 * m1;
                } else {
                    acc += sigm(fmaf(m0, sc0, sh0)) * softp(fmaf(m1, sc1, sh1));
                }
            }
        }
        if constexpr (!STATS) {
            hacc[(size_t)d * 64 + c] = acc;
            s0 += acc; q0 += acc * acc;
        }
    }
    if constexpr (STATS) {
        ((float4*)red)[t] = make_float4(s0, q0, s1, q1);
        __syncthreads();
        if (t < 64) {
            float a0 = 0.f, a1 = 0.f, a2 = 0.f, a3 = 0.f;
            for (int gg = 0; gg < 4; ++gg) {
                const float4 r = ((const float4*)red)[gg * 64 + t];
                a0 += r.x; a1 += r.y; a2 += r.z; a3 += r.w;
            }
            atomicAdd(&ost[t], a0);
            atomicAdd(&ost[C2 + t], a1);
            atomicAdd(&ost[t + 64], a2);
            atomicAdd(&ost[C2 + t + 64], a3);
        }
    } else {
        red[t] = s0; red[256 + t] = q0;
        __syncthreads();
        if (t < 64) {
            float a = 0.f, b2 = 0.f;
            for (int gg = 0; gg < 4; ++gg) {
                a += red[gg * 64 + t];
                b2 += red[256 + gg * 64 + t];
            }
            atomicAdd(&ost[t], a);
            atomicAdd(&ost[64 + t], b2);
        }
    }
}

template <bool STATS>
__global__ __attribute__((amdgpu_waves_per_eu(4, 4))) __launch_bounds__(256)
void k_edge_pass(
    const uint4* __restrict__ efp4, const int* __restrict__ srcp,
    const void* __restrict__ We, const void* __restrict__ be,
    const uint32_t* __restrict__ tsrc, const uint32_t* __restrict__ tdst,
    const float* __restrict__ mss, const int* __restrict__ off,
    float* __restrict__ hacc, float* __restrict__ ost, const int* __restrict__ flag)
{
    __shared__ float red[1024];
    if (*flag) edge_pass_body<TF, STATS>(efp4, srcp, We, be, tsrc, tdst, mss, off, hacc, ost, red);
    else       edge_pass_body<TB, STATS>(efp4, srcp, We, be, tsrc, tdst, mss, off, hacc, ost, red);
}

// ---------------- K6: finalize n-BN -------------------------------------
template <class T>
__device__ __forceinline__ void fin_n_body(const float* nstats, const void* gamma,
                                           const void* beta, float* nss)
{
    const int c = threadIdx.x;  // 64
    const float inv = 1.0f / (float)NNODES;
    const float mean = nstats[c] * inv;
    const float var = fmaxf(nstats[64 + c] * inv - mean * mean, 0.0f);
    const float sc = LD<T>::ld(gamma, c) * rsqrtf(var + BN_EPS);
    nss[c] = sc;
    nss[64 + c] = LD<T>::ld(beta, c) - mean * sc;
}

__global__ void k_fin_n(const float* nstats, const void* gamma, const void* beta,
                        float* nss, const int* flag)
{
    if (*flag) fin_n_body<TF>(nstats, gamma, beta, nss);
    else       fin_n_body<TB>(nstats, gamma, beta, nss);
}

// ---------------- K7: output --------------------------------------------
template <class T>
__device__ __forceinline__ void out_body(const void* node, const float* hacc,
                                         const float* nss, void* out)
{
    const int t = threadIdx.x;
    const int64_t npairs = (int64_t)NNODES * 32;
    int64_t i = (int64_t)blockIdx.x * 256 + t;
    const int c0 = (int)((i * 2) & 63);  // stride is a multiple of 64 elements
    const float sc0 = nss[c0], sh0 = nss[64 + c0];
    const float sc1 = nss[c0 + 1], sh1 = nss[64 + c0 + 1];
    const float2* hp = (const float2*)hacc;
    const int64_t stride = (int64_t)gridDim.x * 256;
    for (; i < npairs; i += stride) {
        const float2 nv = LD<T>::ld2(node, (size_t)(2 * i));
        const float2 h = hp[i];
        const float v0 = softp(nv.x + fmaf(h.x, sc0, sh0));
        const float v1 = softp(nv.y + fmaf(h.y, sc1, sh1));
        LD<T>::st2(out, (size_t)(2 * i), v0, v1);
    }
}

__global__ __launch_bounds__(256) void k_out(const void* node, const float* hacc,
                                             const float* nss, void* out, const int* flag)
{
    if (*flag) out_body<TF>(node, hacc, nss, out);
    else       out_body<TB>(node, hacc, nss, out);
}

extern "C" void kernel_launch(void* const* d_in, const int* in_sizes, int n_in,
                              void* d_out, int out_size, void* d_ws, size_t ws_size,
                              hipStream_t stream)
{
    const void* node = d_in[0];
    const void* ef   = d_in[1];
    const void* Wsrc = d_in[2];
    const void* bsrc = d_in[3];
    const void* Wdst = d_in[4];
    const void* bdst = d_in[5];
    const void* We   = d_in[6];
    const void* be   = d_in[7];
    const void* gm   = d_in[8];
    const void* bm   = d_in[9];
    const void* gn   = d_in[10];
    const void* bn   = d_in[11];
    const int* src   = (const int*)d_in[12];
    const int* dst   = (const int*)d_in[13];

    // ws: hacc(N*64 f32) | mstats(256) | nstats(128) | mss(256) | nss(128) |
    //     flag(4) | tsrc | tdst | cnt(N) | off(N+1) | cur(N) | bsum(512) |
    //     srcp(E) | efp(E*32 bf16, 16B-aligned)   (~187 MB total)
    float* hacc   = (float*)d_ws;
    float* mstats = hacc + (size_t)NNODES * 64;
    float* nstats = mstats + 256;
    float* mss    = nstats + 128;
    float* nss    = mss + 256;
    int* flag     = (int*)(nss + 128);
    bf16* tsrc    = (bf16*)(flag + 4);
    bf16* tdst    = tsrc + (size_t)NNODES * C2;
    int* cnt      = (int*)(tdst + (size_t)NNODES * C2);
    int* off      = cnt + NNODES;
    int* cur      = off + NNODES + 1;
    int* bsum     = cur + NNODES;
    int* srcp     = bsum + 512;
    bf16* efp     = (bf16*)((((uintptr_t)(srcp + NEDGES)) + 15) & ~(uintptr_t)15);

    hipMemsetAsync(mstats, 0, 384 * sizeof(float), stream);
    hipMemsetAsync(cnt, 0, NNODES * sizeof(int), stream);
    k_detect<<<1, 256, 0, stream>>>((const uint32_t*)node, flag);
    // CSR build (enables atomic-free, gather-based edge passes)
    k_hist<<<2048, 256, 0, stream>>>(dst, cnt);
    k_scan1<<<SCAN_B, 256, 0, stream>>>(cnt, bsum);
    k_scan2<<<1, 512, 0, stream>>>(bsum);
    k_scan3<<<SCAN_B, 256, 0, stream>>>(cnt, bsum, off, cur);
    k_fill<<<2048, 256, 0, stream>>>(dst, src, ef, cur, srcp, (uint4*)efp, flag);
    k_tables<<<512, 256, 0, stream>>>(node, Wsrc, bsrc, Wdst, bdst, tsrc, tdst, flag);
    // edge pass 1: m-BN statistics (CSR order, same structure as aggregate)
    k_edge_pass<true><<<2048, 256, 0, stream>>>(
        (const uint4*)efp, srcp, We, be,
        (const uint32_t*)tsrc, (const uint32_t*)tdst,
        mss, off, hacc, mstats, flag);
    k_fin_m<<<1, 128, 0, stream>>>(mstats, gm, bm, mss, flag);
    // edge pass 2: gate + aggregate + fused n-BN statistics
    k_edge_pass<false><<<2048, 256, 0, stream>>>(
        (const uint4*)efp, srcp, We, be,
        (const uint32_t*)tsrc, (const uint32_t*)tdst,
        mss, off, hacc, nstats, flag);
    k_fin_n<<<1, 64, 0, stream>>>(nstats, gn, bn, nss, flag);
    k_out<<<1024, 256, 0, stream>>>(node, hacc, nss, d_out, flag);
}

// Round 5
// 1183.949 us; speedup vs baseline: 1.2087x; 1.0208x over previous
//
#include <hip/hip_runtime.h>
#include <hip/hip_bf16.h>
#include <stdint.h>

#define NNODES 100000
#define NEDGES 1600000
#define C2 128
#define EFEAT 32
#define BN_EPS 1e-5f
#define SCAN_B ((NNODES + 255) / 256)  // 391 blocks for the CSR offset scan

typedef __hip_bfloat16 bf16;

__device__ __forceinline__ float bflo(uint32_t u) { return __uint_as_float(u << 16); }
__device__ __forceinline__ float bfhi(uint32_t u) { return __uint_as_float(u & 0xffff0000u); }
__device__ __forceinline__ float sigm(float x) { return 1.0f / (1.0f + __expf(-x)); }
// softplus via hw v_log_f32: z = exp(-|x|) in (0,1], log(1+z) well-conditioned
__device__ __forceinline__ float softp(float x) { return fmaxf(x, 0.0f) + __logf(1.0f + __expf(-fabsf(x))); }
__device__ __forceinline__ uint32_t pk2(float a, float b) {
    union { bf16 h[2]; uint32_t u; } pk;
    pk.h[0] = __float2bfloat16(a);
    pk.h[1] = __float2bfloat16(b);
    return pk.u;
}

struct TB {};  // tensors are bf16
struct TF {};  // tensors are fp32

template <class T> struct LD;
template <> struct LD<TB> {
    static __device__ __forceinline__ float ld(const void* p, size_t i) {
        return __bfloat162float(((const bf16*)p)[i]);
    }
    static __device__ __forceinline__ float2 ld2(const void* p, size_t i) {
        const uint32_t u = *(const uint32_t*)((const bf16*)p + i);
        return make_float2(bflo(u), bfhi(u));
    }
    static __device__ __forceinline__ void st2(void* p, size_t i, float a, float b) {
        *(uint32_t*)((bf16*)p + i) = pk2(a, b);
    }
    // one 32-feat edge row -> 4 uint4 of packed bf16 (verbatim copy)
    static __device__ __forceinline__ void ldrow(const void* p, size_t e, uint4* o) {
        const uint4* er = (const uint4*)p + e * 4;
        o[0] = er[0]; o[1] = er[1]; o[2] = er[2]; o[3] = er[3];
    }
};
template <> struct LD<TF> {
    static __device__ __forceinline__ float ld(const void* p, size_t i) {
        return ((const float*)p)[i];
    }
    static __device__ __forceinline__ float2 ld2(const void* p, size_t i) {
        return *(const float2*)((const float*)p + i);
    }
    static __device__ __forceinline__ void st2(void* p, size_t i, float a, float b) {
        *(float2*)((float*)p + i) = make_float2(a, b);
    }
    // one 32-feat fp32 edge row -> 4 uint4 of packed bf16
    static __device__ __forceinline__ void ldrow(const void* p, size_t e, uint4* o) {
        const float4* fr = (const float4*)p + e * 8;
#pragma unroll
        for (int j = 0; j < 4; ++j) {
            const float4 a = fr[2 * j], b = fr[2 * j + 1];
            o[j] = make_uint4(pk2(a.x, a.y), pk2(a.z, a.w), pk2(b.x, b.y), pk2(b.z, b.w));
        }
    }
};

// K0: detect dtype. fp32 data read as packed bf16 has huge low-half values.
__global__ void k_detect(const uint32_t* __restrict__ nodeb, int* __restrict__ flag) {
    __shared__ int sfp;
    if (threadIdx.x == 0) sfp = 0;
    __syncthreads();
    const float v = fabsf(bflo(nodeb[threadIdx.x]));
    if (v > 1e10f) sfp = 1;
    __syncthreads();
    if (threadIdx.x == 0) *flag = sfp;
}

// ---------------- CSR build: hist -> scan -> fill(+permute) ---------------
__global__ __launch_bounds__(256) void k_hist(const int* __restrict__ dst,
                                              int* __restrict__ cnt) {
    for (int e = blockIdx.x * 256 + threadIdx.x; e < NEDGES; e += gridDim.x * 256)
        atomicAdd(&cnt[dst[e]], 1);
}

__global__ __launch_bounds__(256) void k_scan1(const int* __restrict__ cnt,
                                               int* __restrict__ bsum) {
    __shared__ int red[256];
    const int t = threadIdx.x;
    const int i = blockIdx.x * 256 + t;
    red[t] = (i < NNODES) ? cnt[i] : 0;
    __syncthreads();
    for (int s = 128; s > 0; s >>= 1) {
        if (t < s) red[t] += red[t + s];
        __syncthreads();
    }
    if (t == 0) bsum[blockIdx.x] = red[0];
}

// single block, 512 threads: exclusive scan of SCAN_B (=391) block sums
__global__ void k_scan2(int* __restrict__ bsum) {
    __shared__ int sh[512];
    const int t = threadIdx.x;
    const int v0 = (t < SCAN_B) ? bsum[t] : 0;
    sh[t] = v0;
    __syncthreads();
    for (int ofs = 1; ofs < 512; ofs <<= 1) {
        const int v = (t >= ofs) ? sh[t - ofs] : 0;
        __syncthreads();
        sh[t] += v;
        __syncthreads();
    }
    if (t < SCAN_B) bsum[t] = sh[t] - v0;  // exclusive
}

__global__ __launch_bounds__(256) void k_scan3(const int* __restrict__ cnt,
                                               const int* __restrict__ bsum,
                                               int* __restrict__ off,
                                               int* __restrict__ cur) {
    __shared__ int sh[256];
    const int t = threadIdx.x;
    const int i = blockIdx.x * 256 + t;
    const int orig = (i < NNODES) ? cnt[i] : 0;
    sh[t] = orig;
    __syncthreads();
    for (int ofs = 1; ofs < 256; ofs <<= 1) {
        const int v = (t >= ofs) ? sh[t - ofs] : 0;
        __syncthreads();
        sh[t] += v;
        __syncthreads();
    }
    const int excl = sh[t] - orig + bsum[blockIdx.x];
    if (i < NNODES) { off[i] = excl; cur[i] = excl; }
    if (i == NNODES) off[NNODES] = excl;  // == NEDGES
}

// fill + fused permute: per edge e at CSR position p, record srcp[p]=src[e]
// and write the bf16 edge-feature row to efp[p]. ef is read exactly once.
template <class T>
__device__ __forceinline__ void fill_body(const int* __restrict__ dst,
                                          const int* __restrict__ src,
                                          const void* __restrict__ ef,
                                          int* __restrict__ cur,
                                          int* __restrict__ srcp,
                                          uint4* __restrict__ efp4)
{
    for (int e = blockIdx.x * 256 + threadIdx.x; e < NEDGES; e += gridDim.x * 256) {
        uint4 o[4];
        LD<T>::ldrow(ef, e, o);
        const int p = atomicAdd(&cur[dst[e]], 1);
        srcp[p] = src[e];
        uint4* w = efp4 + (size_t)p * 4;
        w[0] = o[0]; w[1] = o[1]; w[2] = o[2]; w[3] = o[3];
    }
}

__global__ __launch_bounds__(256) void k_fill(const int* __restrict__ dst,
                                              const int* __restrict__ src,
                                              const void* __restrict__ ef,
                                              int* __restrict__ cur,
                                              int* __restrict__ srcp,
                                              uint4* __restrict__ efp4,
                                              const int* __restrict__ flag)
{
    if (*flag) fill_body<TF>(dst, src, ef, cur, srcp, efp4);
    else       fill_body<TB>(dst, src, ef, cur, srcp, efp4);
}

// ---------------- K1: per-node tables -----------------------------------
template <class T>
__device__ __forceinline__ void tables_body(
    const void* node, const void* Wsrc, const void* bsrc,
    const void* Wdst, const void* bdst, bf16* tsrc, bf16* tdst, float* x)
{
    const int t = threadIdx.x;
    const int col = t & 127;
    const void* W = (t < 128) ? Wsrc : Wdst;
    float w[64];
#pragma unroll
    for (int k = 0; k < 64; ++k) w[k] = LD<T>::ld(W, k * C2 + col);
    const float b = (t < 128) ? LD<T>::ld(bsrc, col) : LD<T>::ld(bdst, col);
    bf16* tab = (t < 128) ? tsrc : tdst;
    const int pos = (col < 64) ? (2 * col) : (2 * col - 127);
    for (int base = blockIdx.x * 4; base < NNODES; base += gridDim.x * 4) {
        x[t] = LD<T>::ld(node, (size_t)base * 64 + t);
        __syncthreads();
        float a0 = b, a1 = b, a2 = b, a3 = b;
#pragma unroll
        for (int k = 0; k < 64; ++k) {
            const float wv = w[k];
            a0 = fmaf(x[k], wv, a0);
            a1 = fmaf(x[64 + k], wv, a1);
            a2 = fmaf(x[128 + k], wv, a2);
            a3 = fmaf(x[192 + k], wv, a3);
        }
        __syncthreads();
        tab[(size_t)(base + 0) * C2 + pos] = __float2bfloat16(a0);
        tab[(size_t)(base + 1) * C2 + pos] = __float2bfloat16(a1);
        tab[(size_t)(base + 2) * C2 + pos] = __float2bfloat16(a2);
        tab[(size_t)(base + 3) * C2 + pos] = __float2bfloat16(a3);
    }
}

__global__ __launch_bounds__(256, 4) void k_tables(
    const void* node, const void* Wsrc, const void* bsrc,
    const void* Wdst, const void* bdst, bf16* tsrc, bf16* tdst, const int* flag)
{
    __shared__ float x[256];
    if (*flag) tables_body<TF>(node, Wsrc, bsrc, Wdst, bdst, tsrc, tdst, x);
    else       tables_body<TB>(node, Wsrc, bsrc, Wdst, bdst, tsrc, tdst, x);
}

// ---------------- K3: finalize m-BN -------------------------------------
template <class T>
__device__ __forceinline__ void fin_m_body(const float* mstats, const void* gamma,
                                           const void* beta, float* mss)
{
    const int c = threadIdx.x;  // 128
    const float inv = 1.0f / (float)NEDGES;
    const float mean = mstats[c] * inv;
    const float var = fmaxf(mstats[C2 + c] * inv - mean * mean, 0.0f);
    const float sc = LD<T>::ld(gamma, c) * rsqrtf(var + BN_EPS);
    mss[c] = sc;
    mss[C2 + c] = LD<T>::ld(beta, c) - mean * sc;
}

__global__ void k_fin_m(const float* mstats, const void* gamma, const void* beta,
                        float* mss, const int* flag)
{
    if (*flag) fin_m_body<TF>(mstats, gamma, beta, mss);
    else       fin_m_body<TB>(mstats, gamma, beta, mss);
}

// ---------------- unified CSR edge pass (STATS / aggregate) ---------------
// R4 post-mortem: VGPR_Count=52 even with __restrict__ + waves_per_eu(4,4)
// -> launch bounds only CAP registers; the allocator still prefers to
// rematerialize the 64 We loads inside the edge loop (cost model, not
// legality). Measured 250 VALU insts/edge vs ~124 ideal = the remat tax.
// v5 fix: asm volatile register pins. A volatile asm can't be duplicated or
// sunk, and its outputs can't be rematerialized -> the 64 weight floats MUST
// be carried live (spill would cost scratch ops; budget 168 VGPR at
// launch_bounds(256,3) makes carrying free). Falsifiable: VGPR must jump
// 52 -> >=110, else this theory is dead and the edge-linear moves to a
// precomputed eW stream.
#define PIN4(v) asm volatile("" : "+v"((v).x), "+v"((v).y), "+v"((v).z), "+v"((v).w));

#define EFMAD(ua, ub, W0v, W1v) {                                   \
    const float fx = bflo(ua), fy = bfhi(ua);                       \
    const float fz = bflo(ub), fw = bfhi(ub);                       \
    el0 = fmaf(fx, (W0v).x, el0); el1 = fmaf(fx, (W1v).x, el1);     \
    el0 = fmaf(fy, (W0v).y, el0); el1 = fmaf(fy, (W1v).y, el1);     \
    el0 = fmaf(fz, (W0v).z, el0); el1 = fmaf(fz, (W1v).z, el1);     \
    el0 = fmaf(fw, (W0v).w, el0); el1 = fmaf(fw, (W1v).w, el1); }

#define LDW(j)                                                                 \
    float4 W0##j = make_float4(LD<T>::ld(We, (4 * j + 0) * C2 + c),            \
                               LD<T>::ld(We, (4 * j + 1) * C2 + c),            \
                               LD<T>::ld(We, (4 * j + 2) * C2 + c),            \
                               LD<T>::ld(We, (4 * j + 3) * C2 + c));           \
    float4 W1##j = make_float4(LD<T>::ld(We, (4 * j + 0) * C2 + c + 64),       \
                               LD<T>::ld(We, (4 * j + 1) * C2 + c + 64),       \
                               LD<T>::ld(We, (4 * j + 2) * C2 + c + 64),       \
                               LD<T>::ld(We, (4 * j + 3) * C2 + c + 64));

template <class T, bool STATS>
__device__ __forceinline__ void edge_pass_body(
    const uint4* __restrict__ efp4, const int* __restrict__ srcp,
    const void* __restrict__ We, const void* __restrict__ be,
    const uint32_t* __restrict__ tsrc, const uint32_t* __restrict__ tdst,
    const float* __restrict__ mss, const int* __restrict__ off,
    float* __restrict__ hacc, float* __restrict__ ost, float* __restrict__ red)
{
    const int t = threadIdx.x;
    const int c = t & 63;
    const int g = t >> 6;  // wave id within block; one wave = one node
    LDW(0) LDW(1) LDW(2) LDW(3) LDW(4) LDW(5) LDW(6) LDW(7)
    // register pins: forbid remat/sinking of the 64 weight values
    PIN4(W00) PIN4(W01) PIN4(W02) PIN4(W03) PIN4(W04) PIN4(W05) PIN4(W06) PIN4(W07)
    PIN4(W10) PIN4(W11) PIN4(W12) PIN4(W13) PIN4(W14) PIN4(W15) PIN4(W16) PIN4(W17)
    const float be0 = LD<T>::ld(be, c), be1 = LD<T>::ld(be, c + 64);
    float sc0 = 0.f, sh0 = 0.f, sc1 = 0.f, sh1 = 0.f;
    if constexpr (!STATS) {
        sc0 = mss[c];      sh0 = mss[C2 + c];
        sc1 = mss[c + 64]; sh1 = mss[C2 + c + 64];
    }
    float s0 = 0.f, q0 = 0.f, s1 = 0.f, q1 = 0.f;
    for (int d0 = blockIdx.x * 4; d0 < NNODES; d0 += gridDim.x * 4) {
        const int d = d0 + g;  // wave-uniform (NNODES % 4 == 0)
        const uint32_t ud = tdst[(size_t)d * 64 + c];
        const float hd0 = bflo(ud), hd1 = bfhi(ud);
        const int beg = __builtin_amdgcn_readfirstlane(off[d]);
        const int end = __builtin_amdgcn_readfirstlane(off[d + 1]);
        float acc = 0.f;
        for (int b = beg; b < end; b += 64) {
            const int nb = min(64, end - b);
            const int sb = (b + c < end) ? srcp[b + c] : 0;
            uint4 n0, n1, n2, n3;
            {
                const uint4* rp = efp4 + (size_t)b * 4;
                n0 = rp[0]; n1 = rp[1]; n2 = rp[2]; n3 = rp[3];
            }
            // readlane: src id to SGPR -> tsrc row addr is SGPR-base + c*4
            uint32_t usn = tsrc[(size_t)__builtin_amdgcn_readlane(sb, 0) * 64 + c];
            for (int i = 0; i < nb; ++i) {
                const uint4 r0 = n0, r1 = n1, r2 = n2, r3 = n3;
                const uint32_t us = usn;
                if (i + 1 < nb) {  // wave-uniform branch
                    const uint4* rp = efp4 + (size_t)(b + i + 1) * 4;
                    n0 = rp[0]; n1 = rp[1]; n2 = rp[2]; n3 = rp[3];
                    usn = tsrc[(size_t)__builtin_amdgcn_readlane(sb, i + 1) * 64 + c];
                }
                float el0 = be0, el1 = be1;
                EFMAD(r0.x, r0.y, W00, W10) EFMAD(r0.z, r0.w, W01, W11)
                EFMAD(r1.x, r1.y, W02, W12) EFMAD(r1.z, r1.w, W03, W13)
                EFMAD(r2.x, r2.y, W04, W14) EFMAD(r2.z, r2.w, W05, W15)
                EFMAD(r3.x, r3.y, W06, W16) EFMAD(r3.z, r3.w, W07, W17)
                const float m0 = el0 + bflo(us) + hd0;
                const float m1 = el1 + bfhi(us) + hd1;
                if constexpr (STATS) {
                    s0 += m0; q0 += m0 * m0;
                    s1 += m1; q1 += m1 * m1;
                } else {
                    acc += sigm(fmaf(m0, sc0, sh0)) * softp(fmaf(m1, sc1, sh1));
                }
            }
        }
        if constexpr (!STATS) {
            hacc[(size_t)d * 64 + c] = acc;
            s0 += acc; q0 += acc * acc;
        }
    }
    if constexpr (STATS) {
        ((float4*)red)[t] = make_float4(s0, q0, s1, q1);
        __syncthreads();
        if (t < 64) {
            float a0 = 0.f, a1 = 0.f, a2 = 0.f, a3 = 0.f;
            for (int gg = 0; gg < 4; ++gg) {
                const float4 r = ((const float4*)red)[gg * 64 + t];
                a0 += r.x; a1 += r.y; a2 += r.z; a3 += r.w;
            }
            atomicAdd(&ost[t], a0);
            atomicAdd(&ost[C2 + t], a1);
            atomicAdd(&ost[t + 64], a2);
            atomicAdd(&ost[C2 + t + 64], a3);
        }
    } else {
        red[t] = s0; red[256 + t] = q0;
        __syncthreads();
        if (t < 64) {
            float a = 0.f, b2 = 0.f;
            for (int gg = 0; gg < 4; ++gg) {
                a += red[gg * 64 + t];
                b2 += red[256 + gg * 64 + t];
            }
            atomicAdd(&ost[t], a);
            atomicAdd(&ost[64 + t], b2);
        }
    }
}

template <bool STATS>
__global__ __launch_bounds__(256, 3)  // min 3 waves/EU -> 168-VGPR cap
void k_edge_pass(
    const uint4* __restrict__ efp4, const int* __restrict__ srcp,
    const void* __restrict__ We, const void* __restrict__ be,
    const uint32_t* __restrict__ tsrc, const uint32_t* __restrict__ tdst,
    const float* __restrict__ mss, const int* __restrict__ off,
    float* __restrict__ hacc, float* __restrict__ ost, const int* __restrict__ flag)
{
    __shared__ float red[1024];
    if (*flag) edge_pass_body<TF, STATS>(efp4, srcp, We, be, tsrc, tdst, mss, off, hacc, ost, red);
    else       edge_pass_body<TB, STATS>(efp4, srcp, We, be, tsrc, tdst, mss, off, hacc, ost, red);
}

// ---------------- K6: finalize n-BN -------------------------------------
template <class T>
__device__ __forceinline__ void fin_n_body(const float* nstats, const void* gamma,
                                           const void* beta, float* nss)
{
    const int c = threadIdx.x;  // 64
    const float inv = 1.0f / (float)NNODES;
    const float mean = nstats[c] * inv;
    const float var = fmaxf(nstats[64 + c] * inv - mean * mean, 0.0f);
    const float sc = LD<T>::ld(gamma, c) * rsqrtf(var + BN_EPS);
    nss[c] = sc;
    nss[64 + c] = LD<T>::ld(beta, c) - mean * sc;
}

__global__ void k_fin_n(const float* nstats, const void* gamma, const void* beta,
                        float* nss, const int* flag)
{
    if (*flag) fin_n_body<TF>(nstats, gamma, beta, nss);
    else       fin_n_body<TB>(nstats, gamma, beta, nss);
}

// ---------------- K7: output --------------------------------------------
template <class T>
__device__ __forceinline__ void out_body(const void* node, const float* hacc,
                                         const float* nss, void* out)
{
    const int t = threadIdx.x;
    const int64_t npairs = (int64_t)NNODES * 32;
    int64_t i = (int64_t)blockIdx.x * 256 + t;
    const int c0 = (int)((i * 2) & 63);  // stride is a multiple of 64 elements
    const float sc0 = nss[c0], sh0 = nss[64 + c0];
    const float sc1 = nss[c0 + 1], sh1 = nss[64 + c0 + 1];
    const float2* hp = (const float2*)hacc;
    const int64_t stride = (int64_t)gridDim.x * 256;
    for (; i < npairs; i += stride) {
        const float2 nv = LD<T>::ld2(node, (size_t)(2 * i));
        const float2 h = hp[i];
        const float v0 = softp(nv.x + fmaf(h.x, sc0, sh0));
        const float v1 = softp(nv.y + fmaf(h.y, sc1, sh1));
        LD<T>::st2(out, (size_t)(2 * i), v0, v1);
    }
}

__global__ __launch_bounds__(256) void k_out(const void* node, const float* hacc,
                                             const float* nss, void* out, const int* flag)
{
    if (*flag) out_body<TF>(node, hacc, nss, out);
    else       out_body<TB>(node, hacc, nss, out);
}

extern "C" void kernel_launch(void* const* d_in, const int* in_sizes, int n_in,
                              void* d_out, int out_size, void* d_ws, size_t ws_size,
                              hipStream_t stream)
{
    const void* node = d_in[0];
    const void* ef   = d_in[1];
    const void* Wsrc = d_in[2];
    const void* bsrc = d_in[3];
    const void* Wdst = d_in[4];
    const void* bdst = d_in[5];
    const void* We   = d_in[6];
    const void* be   = d_in[7];
    const void* gm   = d_in[8];
    const void* bm   = d_in[9];
    const void* gn   = d_in[10];
    const void* bn   = d_in[11];
    const int* src   = (const int*)d_in[12];
    const int* dst   = (const int*)d_in[13];

    // ws: hacc(N*64 f32) | mstats(256) | nstats(128) | mss(256) | nss(128) |
    //     flag(4) | tsrc | tdst | cnt(N) | off(N+1) | cur(N) | bsum(512) |
    //     srcp(E) | efp(E*32 bf16, 16B-aligned)   (~187 MB total)
    float* hacc   = (float*)d_ws;
    float* mstats = hacc + (size_t)NNODES * 64;
    float* nstats = mstats + 256;
    float* mss    = nstats + 128;
    float* nss    = mss + 256;
    int* flag     = (int*)(nss + 128);
    bf16* tsrc    = (bf16*)(flag + 4);
    bf16* tdst    = tsrc + (size_t)NNODES * C2;
    int* cnt      = (int*)(tdst + (size_t)NNODES * C2);
    int* off      = cnt + NNODES;
    int* cur      = off + NNODES + 1;
    int* bsum     = cur + NNODES;
    int* srcp     = bsum + 512;
    bf16* efp     = (bf16*)((((uintptr_t)(srcp + NEDGES)) + 15) & ~(uintptr_t)15);

    hipMemsetAsync(mstats, 0, 384 * sizeof(float), stream);
    hipMemsetAsync(cnt, 0, NNODES * sizeof(int), stream);
    k_detect<<<1, 256, 0, stream>>>((const uint32_t*)node, flag);
    // CSR build (enables atomic-free, gather-based edge passes)
    k_hist<<<2048, 256, 0, stream>>>(dst, cnt);
    k_scan1<<<SCAN_B, 256, 0, stream>>>(cnt, bsum);
    k_scan2<<<1, 512, 0, stream>>>(bsum);
    k_scan3<<<SCAN_B, 256, 0, stream>>>(cnt, bsum, off, cur);
    k_fill<<<2048, 256, 0, stream>>>(dst, src, ef, cur, srcp, (uint4*)efp, flag);
    k_tables<<<512, 256, 0, stream>>>(node, Wsrc, bsrc, Wdst, bdst, tsrc, tdst, flag);
    // edge pass 1: m-BN statistics (CSR order, same structure as aggregate)
    k_edge_pass<true><<<2048, 256, 0, stream>>>(
        (const uint4*)efp, srcp, We, be,
        (const uint32_t*)tsrc, (const uint32_t*)tdst,
        mss, off, hacc, mstats, flag);
    k_fin_m<<<1, 128, 0, stream>>>(mstats, gm, bm, mss, flag);
    // edge pass 2: gate + aggregate + fused n-BN statistics
    k_edge_pass<false><<<2048, 256, 0, stream>>>(
        (const uint4*)efp, srcp, We, be,
        (const uint32_t*)tsrc, (const uint32_t*)tdst,
        mss, off, hacc, nstats, flag);
    k_fin_n<<<1, 64, 0, stream>>>(nstats, gn, bn, nss, flag);
    k_out<<<1024, 256, 0, stream>>>(node, hacc, nss, d_out, flag);
}

// Round 7
// 1071.711 us; speedup vs baseline: 1.3353x; 1.1047x over previous
//
#include <hip/hip_runtime.h>
#include <hip/hip_bf16.h>
#include <stdint.h>

#define NNODES 100000
#define NEDGES 1600000
#define C2 128
#define EFEAT 32
#define BN_EPS 1e-5f
#define SCAN_B ((NNODES + 255) / 256)  // 391 blocks for the CSR offset scan

typedef __hip_bfloat16 bf16;
typedef __attribute__((ext_vector_type(8))) short bf16x8;
typedef __attribute__((ext_vector_type(4))) float f32x4;

union U8 { uint4 u; bf16x8 h; };

__device__ __forceinline__ float bflo(uint32_t u) { return __uint_as_float(u << 16); }
__device__ __forceinline__ float bfhi(uint32_t u) { return __uint_as_float(u & 0xffff0000u); }
__device__ __forceinline__ float sigm(float x) { return 1.0f / (1.0f + __expf(-x)); }
__device__ __forceinline__ float softp(float x) { return fmaxf(x, 0.0f) + __logf(1.0f + __expf(-fabsf(x))); }
__device__ __forceinline__ uint32_t pk2(float a, float b) {
    union { bf16 h[2]; uint32_t u; } pk;
    pk.h[0] = __float2bfloat16(a);
    pk.h[1] = __float2bfloat16(b);
    return pk.u;
}
__device__ __forceinline__ f32x4 mfma16(bf16x8 a, bf16x8 b, f32x4 c) {
    return __builtin_amdgcn_mfma_f32_16x16x32_bf16(a, b, c, 0, 0, 0);
}

struct TB {};  // tensors are bf16
struct TF {};  // tensors are fp32

template <class T> struct LD;
template <> struct LD<TB> {
    static __device__ __forceinline__ float ld(const void* p, size_t i) {
        return __bfloat162float(((const bf16*)p)[i]);
    }
    static __device__ __forceinline__ float2 ld2(const void* p, size_t i) {
        const uint32_t u = *(const uint32_t*)((const bf16*)p + i);
        return make_float2(bflo(u), bfhi(u));
    }
    static __device__ __forceinline__ void st2(void* p, size_t i, float a, float b) {
        *(uint32_t*)((bf16*)p + i) = pk2(a, b);
    }
    // one 32-feat edge row -> 4 uint4 of packed bf16 (verbatim copy)
    static __device__ __forceinline__ void ldrow(const void* p, size_t e, uint4* o) {
        const uint4* er = (const uint4*)p + e * 4;
        o[0] = er[0]; o[1] = er[1]; o[2] = er[2]; o[3] = er[3];
    }
};
template <> struct LD<TF> {
    static __device__ __forceinline__ float ld(const void* p, size_t i) {
        return ((const float*)p)[i];
    }
    static __device__ __forceinline__ float2 ld2(const void* p, size_t i) {
        return *(const float2*)((const float*)p + i);
    }
    static __device__ __forceinline__ void st2(void* p, size_t i, float a, float b) {
        *(float2*)((float*)p + i) = make_float2(a, b);
    }
    // one 32-feat fp32 edge row -> 4 uint4 of packed bf16
    static __device__ __forceinline__ void ldrow(const void* p, size_t e, uint4* o) {
        const float4* fr = (const float4*)p + e * 8;
#pragma unroll
        for (int j = 0; j < 4; ++j) {
            const float4 a = fr[2 * j], b = fr[2 * j + 1];
            o[j] = make_uint4(pk2(a.x, a.y), pk2(a.z, a.w), pk2(b.x, b.y), pk2(b.z, b.w));
        }
    }
};

// K0: detect dtype. fp32 data read as packed bf16 has huge low-half values.
__global__ void k_detect(const uint32_t* __restrict__ nodeb, int* __restrict__ flag) {
    __shared__ int sfp;
    if (threadIdx.x == 0) sfp = 0;
    __syncthreads();
    const float v = fabsf(bflo(nodeb[threadIdx.x]));
    if (v > 1e10f) sfp = 1;
    __syncthreads();
    if (threadIdx.x == 0) *flag = sfp;
}

// ---------------- CSR build: hist -> scan -> fill(+permute) ---------------
__global__ __launch_bounds__(256) void k_hist(const int* __restrict__ dst,
                                              int* __restrict__ cnt) {
    for (int e = blockIdx.x * 256 + threadIdx.x; e < NEDGES; e += gridDim.x * 256)
        atomicAdd(&cnt[dst[e]], 1);
}

__global__ __launch_bounds__(256) void k_scan1(const int* __restrict__ cnt,
                                               int* __restrict__ bsum) {
    __shared__ int red[256];
    const int t = threadIdx.x;
    const int i = blockIdx.x * 256 + t;
    red[t] = (i < NNODES) ? cnt[i] : 0;
    __syncthreads();
    for (int s = 128; s > 0; s >>= 1) {
        if (t < s) red[t] += red[t + s];
        __syncthreads();
    }
    if (t == 0) bsum[blockIdx.x] = red[0];
}

__global__ void k_scan2(int* __restrict__ bsum) {
    __shared__ int sh[512];
    const int t = threadIdx.x;
    const int v0 = (t < SCAN_B) ? bsum[t] : 0;
    sh[t] = v0;
    __syncthreads();
    for (int ofs = 1; ofs < 512; ofs <<= 1) {
        const int v = (t >= ofs) ? sh[t - ofs] : 0;
        __syncthreads();
        sh[t] += v;
        __syncthreads();
    }
    if (t < SCAN_B) bsum[t] = sh[t] - v0;  // exclusive
}

__global__ __launch_bounds__(256) void k_scan3(const int* __restrict__ cnt,
                                               const int* __restrict__ bsum,
                                               int* __restrict__ off,
                                               int* __restrict__ cur) {
    __shared__ int sh[256];
    const int t = threadIdx.x;
    const int i = blockIdx.x * 256 + t;
    const int orig = (i < NNODES) ? cnt[i] : 0;
    sh[t] = orig;
    __syncthreads();
    for (int ofs = 1; ofs < 256; ofs <<= 1) {
        const int v = (t >= ofs) ? sh[t - ofs] : 0;
        __syncthreads();
        sh[t] += v;
        __syncthreads();
    }
    const int excl = sh[t] - orig + bsum[blockIdx.x];
    if (i < NNODES) { off[i] = excl; cur[i] = excl; }
    if (i == NNODES) off[NNODES] = excl;  // == NEDGES
}

// fill + fused permute: per edge e at CSR position p, record srcp[p]=src[e]
// and write the bf16 edge-feature row to efp[p]. ef read exactly once.
template <class T>
__device__ __forceinline__ void fill_body(const int* __restrict__ dst,
                                          const int* __restrict__ src,
                                          const void* __restrict__ ef,
                                          int* __restrict__ cur,
                                          int* __restrict__ srcp,
                                          uint4* __restrict__ efp4)
{
    for (int e = blockIdx.x * 256 + threadIdx.x; e < NEDGES; e += gridDim.x * 256) {
        uint4 o[4];
        LD<T>::ldrow(ef, e, o);
        const int p = atomicAdd(&cur[dst[e]], 1);
        srcp[p] = src[e];
        uint4* w = efp4 + (size_t)p * 4;
        w[0] = o[0]; w[1] = o[1]; w[2] = o[2]; w[3] = o[3];
    }
}

__global__ __launch_bounds__(256) void k_fill(const int* __restrict__ dst,
                                              const int* __restrict__ src,
                                              const void* __restrict__ ef,
                                              int* __restrict__ cur,
                                              int* __restrict__ srcp,
                                              uint4* __restrict__ efp4,
                                              const int* __restrict__ flag)
{
    if (*flag) fill_body<TF>(dst, src, ef, cur, srcp, efp4);
    else       fill_body<TB>(dst, src, ef, cur, srcp, efp4);
}

// ---------------- K_prepw: We -> B-fragment order (8 KB) ------------------
// B-frag for tile n: lane l holds We[(l>>4)*8+j][n*16 + (l&15)], j=0..7.
template <class T>
__device__ __forceinline__ void prepw_body(const void* __restrict__ We,
                                           uint4* __restrict__ Wep4)
{
    const int t = threadIdx.x;  // 512 threads: one (n, lane) pair each
    const int n = t >> 6, l = t & 63;
    const int col = l & 15, kg = l >> 4;
    float w[8];
#pragma unroll
    for (int j = 0; j < 8; ++j)
        w[j] = LD<T>::ld(We, (size_t)(kg * 8 + j) * C2 + n * 16 + col);
    Wep4[n * 64 + l] = make_uint4(pk2(w[0], w[1]), pk2(w[2], w[3]),
                                  pk2(w[4], w[5]), pk2(w[6], w[7]));
}

__global__ void k_prepw(const void* __restrict__ We, uint4* __restrict__ Wep4,
                        const int* __restrict__ flag)
{
    if (*flag) prepw_body<TF>(We, Wep4);
    else       prepw_body<TB>(We, Wep4);
}

// ---------------- K1: per-node tables (unchanged) -------------------------
template <class T>
__device__ __forceinline__ void tables_body(
    const void* node, const void* Wsrc, const void* bsrc,
    const void* Wdst, const void* bdst, bf16* tsrc, bf16* tdst, float* x)
{
    const int t = threadIdx.x;
    const int col = t & 127;
    const void* W = (t < 128) ? Wsrc : Wdst;
    float w[64];
#pragma unroll
    for (int k = 0; k < 64; ++k) w[k] = LD<T>::ld(W, k * C2 + col);
    const float b = (t < 128) ? LD<T>::ld(bsrc, col) : LD<T>::ld(bdst, col);
    bf16* tab = (t < 128) ? tsrc : tdst;
    const int pos = (col < 64) ? (2 * col) : (2 * col - 127);
    for (int base = blockIdx.x * 4; base < NNODES; base += gridDim.x * 4) {
        x[t] = LD<T>::ld(node, (size_t)base * 64 + t);
        __syncthreads();
        float a0 = b, a1 = b, a2 = b, a3 = b;
#pragma unroll
        for (int k = 0; k < 64; ++k) {
            const float wv = w[k];
            a0 = fmaf(x[k], wv, a0);
            a1 = fmaf(x[64 + k], wv, a1);
            a2 = fmaf(x[128 + k], wv, a2);
            a3 = fmaf(x[192 + k], wv, a3);
        }
        __syncthreads();
        tab[(size_t)(base + 0) * C2 + pos] = __float2bfloat16(a0);
        tab[(size_t)(base + 1) * C2 + pos] = __float2bfloat16(a1);
        tab[(size_t)(base + 2) * C2 + pos] = __float2bfloat16(a2);
        tab[(size_t)(base + 3) * C2 + pos] = __float2bfloat16(a3);
    }
}

__global__ __launch_bounds__(256, 4) void k_tables(
    const void* node, const void* Wsrc, const void* bsrc,
    const void* Wdst, const void* bdst, bf16* tsrc, bf16* tdst, const int* flag)
{
    __shared__ float x[256];
    if (*flag) tables_body<TF>(node, Wsrc, bsrc, Wdst, bdst, tsrc, tdst, x);
    else       tables_body<TB>(node, Wsrc, bsrc, Wdst, bdst, tsrc, tdst, x);
}

// ---------------- K3: finalize m-BN -------------------------------------
template <class T>
__device__ __forceinline__ void fin_m_body(const float* mstats, const void* gamma,
                                           const void* beta, float* mss)
{
    const int c = threadIdx.x;  // 128
    const float inv = 1.0f / (float)NEDGES;
    const float mean = mstats[c] * inv;
    const float var = fmaxf(mstats[C2 + c] * inv - mean * mean, 0.0f);
    const float sc = LD<T>::ld(gamma, c) * rsqrtf(var + BN_EPS);
    mss[c] = sc;
    mss[C2 + c] = LD<T>::ld(beta, c) - mean * sc;
}

__global__ void k_fin_m(const float* mstats, const void* gamma, const void* beta,
                        float* mss, const int* flag)
{
    if (*flag) fin_m_body<TF>(mstats, gamma, beta, mss);
    else       fin_m_body<TB>(mstats, gamma, beta, mss);
}

// ---------------- unified MFMA CSR edge pass (STATS / aggregate) -----------
// R6 post-mortem: gbuf overflowed ws (~295 MB vs ~190 avail) -> GPU fault
// masquerading as "container failed twice". v7: same MFMA core, ZERO extra
// workspace: wave-per-node over the CSR edge list (R4 layout, 186.8 MB).
// Per 16-edge group of a node: A-frag = 16 efp rows (sequential bf16),
// B-frags = 8 resident Wep fragments (32 VGPRs, vector operands -> the
// R2-R5 scalar-remat tax is structurally gone), 8 mfma_f32_16x16x32_bf16.
// C layout (m89-verified): col=lane&15, row=(lane>>4)*4+reg. Lane (kg,r16)
// owns edges e0+kg*4+r, channels n*16+r16 (acc[n]=L half, acc[n+4]=H half;
// pair-interleaved tables: dword ch of a row = (ch lo | ch+64 hi)).
// tdst row: loaded once per NODE (was once per edge). Tail edges predicated.
template <class T, bool STATS>
__device__ __forceinline__ void edge_pass_body(
    const uint4* __restrict__ efp4, const int* __restrict__ srcp,
    const uint4* __restrict__ Wep4, const void* __restrict__ be,
    const uint32_t* __restrict__ ts32, const uint32_t* __restrict__ td32,
    const float* __restrict__ mss, const int* __restrict__ off,
    float* __restrict__ hacc, float* __restrict__ ost, float* __restrict__ red)
{
    const int t = threadIdx.x;
    const int lane = t & 63, wv = t >> 6;
    const int r16 = lane & 15, kg = lane >> 4;
    U8 b[8];
#pragma unroll
    for (int n = 0; n < 8; ++n) b[n].u = Wep4[n * 64 + lane];
    float beL[4], beH[4], scL[4], shL[4], scH[4], shH[4];
#pragma unroll
    for (int n = 0; n < 4; ++n) {
        const int ch = n * 16 + r16;
        beL[n] = LD<T>::ld(be, ch);
        beH[n] = LD<T>::ld(be, ch + 64);
        if constexpr (!STATS) {
            scL[n] = mss[ch];       shL[n] = mss[C2 + ch];
            scH[n] = mss[ch + 64];  shH[n] = mss[C2 + ch + 64];
        }
    }
    float sL[4] = {0,0,0,0}, qL[4] = {0,0,0,0};
    float sH[4] = {0,0,0,0}, qH[4] = {0,0,0,0};   // STATS accumulators
    float ns[4] = {0,0,0,0}, nq[4] = {0,0,0,0};   // n-BN accumulators (lanes<16)
    const f32x4 zero = {0.f, 0.f, 0.f, 0.f};
    for (int d0 = blockIdx.x * 4; d0 < NNODES; d0 += gridDim.x * 4) {
        const int d = d0 + wv;  // wave-uniform (NNODES % 4 == 0)
        const int beg = __builtin_amdgcn_readfirstlane(off[d]);
        const int end = __builtin_amdgcn_readfirstlane(off[d + 1]);
        uint32_t ud[4];
#pragma unroll
        for (int n = 0; n < 4; ++n) ud[n] = td32[(size_t)d * 64 + n * 16 + r16];
        float gacc[4] = {0.f, 0.f, 0.f, 0.f};
        for (int e0 = beg; e0 < end; e0 += 16) {
            const int arow = min(e0 + r16, NEDGES - 1);
            U8 a; a.u = efp4[(size_t)arow * 4 + kg];
            f32x4 acc[8];
#pragma unroll
            for (int n = 0; n < 8; ++n) acc[n] = mfma16(a.h, b[n].h, zero);
#pragma unroll
            for (int r = 0; r < 4; ++r) {
                const int e = e0 + kg * 4 + r;
                const bool valid = (e < end);
                const int sn = srcp[valid ? e : beg];
                const uint32_t* bs = ts32 + (size_t)sn * 64;
#pragma unroll
                for (int n = 0; n < 4; ++n) {
                    const uint32_t us = bs[n * 16 + r16];
                    const float m0 = acc[n][r] + beL[n] + bflo(us) + bflo(ud[n]);
                    const float m1 = acc[n + 4][r] + beH[n] + bfhi(us) + bfhi(ud[n]);
                    if constexpr (STATS) {
                        const float m0v = valid ? m0 : 0.f;
                        const float m1v = valid ? m1 : 0.f;
                        sL[n] += m0v; qL[n] += m0v * m0v;
                        sH[n] += m1v; qH[n] += m1v * m1v;
                    } else {
                        const float g = sigm(fmaf(m0, scL[n], shL[n])) *
                                        softp(fmaf(m1, scH[n], shH[n]));
                        gacc[n] += valid ? g : 0.f;
                    }
                }
            }
        }
        if constexpr (!STATS) {
#pragma unroll
            for (int n = 0; n < 4; ++n) {
                gacc[n] += __shfl_xor(gacc[n], 16);
                gacc[n] += __shfl_xor(gacc[n], 32);
            }
            if (lane < 16) {
#pragma unroll
                for (int n = 0; n < 4; ++n) {
                    hacc[(size_t)d * 64 + n * 16 + r16] = gacc[n];
                    ns[n] += gacc[n];
                    nq[n] += gacc[n] * gacc[n];
                }
            }
        }
    }
    if constexpr (STATS) {
        float vals[16];
#pragma unroll
        for (int n = 0; n < 4; ++n) {
            vals[n * 4 + 0] = sL[n]; vals[n * 4 + 1] = qL[n];
            vals[n * 4 + 2] = sH[n]; vals[n * 4 + 3] = qH[n];
        }
#pragma unroll
        for (int v = 0; v < 16; ++v) {
            vals[v] += __shfl_xor(vals[v], 16);
            vals[v] += __shfl_xor(vals[v], 32);
        }
        if (lane < 16) {
#pragma unroll
            for (int v = 0; v < 16; ++v) red[wv * 256 + r16 * 16 + v] = vals[v];
        }
        __syncthreads();
        {   // 256 threads: one (col, v) pair each; sum the 4 waves; one atomic
            const int col = t >> 4, v = t & 15;
            const int n = v >> 2, part = v & 3;
            float s = 0.f;
#pragma unroll
            for (int w = 0; w < 4; ++w) s += red[w * 256 + col * 16 + v];
            const int ch = n * 16 + col;
            int idx;
            if (part == 0) idx = ch;
            else if (part == 1) idx = C2 + ch;
            else if (part == 2) idx = ch + 64;
            else idx = C2 + ch + 64;
            atomicAdd(&ost[idx], s);
        }
    } else {
        if (lane < 16) {
#pragma unroll
            for (int n = 0; n < 4; ++n) {
                red[wv * 128 + r16 * 8 + n] = ns[n];
                red[wv * 128 + r16 * 8 + 4 + n] = nq[n];
            }
        }
        __syncthreads();
        if (t < 128) {
            float s = 0.f;
#pragma unroll
            for (int w = 0; w < 4; ++w) s += red[w * 128 + t];
            const int r16d = t >> 3, rest = t & 7;
            const int n = rest & 3, isq = rest >> 2;
            const int ch = n * 16 + r16d;
            atomicAdd(&ost[isq * 64 + ch], s);
        }
    }
}

template <bool STATS>
__global__ __launch_bounds__(256, 3) void k_edge_pass(
    const uint4* __restrict__ efp4, const int* __restrict__ srcp,
    const uint4* __restrict__ Wep4, const void* __restrict__ be,
    const uint32_t* __restrict__ ts32, const uint32_t* __restrict__ td32,
    const float* __restrict__ mss, const int* __restrict__ off,
    float* __restrict__ hacc, float* __restrict__ ost, const int* __restrict__ flag)
{
    __shared__ float red[1024];
    if (*flag) edge_pass_body<TF, STATS>(efp4, srcp, Wep4, be, ts32, td32, mss, off, hacc, ost, red);
    else       edge_pass_body<TB, STATS>(efp4, srcp, Wep4, be, ts32, td32, mss, off, hacc, ost, red);
}

// ---------------- K6: finalize n-BN -------------------------------------
template <class T>
__device__ __forceinline__ void fin_n_body(const float* nstats, const void* gamma,
                                           const void* beta, float* nss)
{
    const int c = threadIdx.x;  // 64
    const float inv = 1.0f / (float)NNODES;
    const float mean = nstats[c] * inv;
    const float var = fmaxf(nstats[64 + c] * inv - mean * mean, 0.0f);
    const float sc = LD<T>::ld(gamma, c) * rsqrtf(var + BN_EPS);
    nss[c] = sc;
    nss[64 + c] = LD<T>::ld(beta, c) - mean * sc;
}

__global__ void k_fin_n(const float* nstats, const void* gamma, const void* beta,
                        float* nss, const int* flag)
{
    if (*flag) fin_n_body<TF>(nstats, gamma, beta, nss);
    else       fin_n_body<TB>(nstats, gamma, beta, nss);
}

// ---------------- K7: output --------------------------------------------
template <class T>
__device__ __forceinline__ void out_body(const void* node, const float* hacc,
                                         const float* nss, void* out)
{
    const int t = threadIdx.x;
    const int64_t npairs = (int64_t)NNODES * 32;
    int64_t i = (int64_t)blockIdx.x * 256 + t;
    const int c0 = (int)((i * 2) & 63);  // stride is a multiple of 64 elements
    const float sc0 = nss[c0], sh0 = nss[64 + c0];
    const float sc1 = nss[c0 + 1], sh1 = nss[64 + c0 + 1];
    const float2* hp = (const float2*)hacc;
    const int64_t stride = (int64_t)gridDim.x * 256;
    for (; i < npairs; i += stride) {
        const float2 nv = LD<T>::ld2(node, (size_t)(2 * i));
        const float2 h = hp[i];
        const float v0 = softp(nv.x + fmaf(h.x, sc0, sh0));
        const float v1 = softp(nv.y + fmaf(h.y, sc1, sh1));
        LD<T>::st2(out, (size_t)(2 * i), v0, v1);
    }
}

__global__ __launch_bounds__(256) void k_out(const void* node, const float* hacc,
                                             const float* nss, void* out, const int* flag)
{
    if (*flag) out_body<TF>(node, hacc, nss, out);
    else       out_body<TB>(node, hacc, nss, out);
}

extern "C" void kernel_launch(void* const* d_in, const int* in_sizes, int n_in,
                              void* d_out, int out_size, void* d_ws, size_t ws_size,
                              hipStream_t stream)
{
    const void* node = d_in[0];
    const void* ef   = d_in[1];
    const void* Wsrc = d_in[2];
    const void* bsrc = d_in[3];
    const void* Wdst = d_in[4];
    const void* bdst = d_in[5];
    const void* We   = d_in[6];
    const void* be   = d_in[7];
    const void* gm   = d_in[8];
    const void* bm   = d_in[9];
    const void* gn   = d_in[10];
    const void* bn   = d_in[11];
    const int* src   = (const int*)d_in[12];
    const int* dst   = (const int*)d_in[13];

    // ws: hacc(25.6M) | mstats | nstats | mss | nss | flag | tsrc+tdst(51.2M)
    //     | cnt | off | cur | bsum | srcp(6.4M) | efp(102.4M) | Wep(8K)
    //     total ~186.9 MB == R4's proven footprint (+8 KB)
    float* hacc   = (float*)d_ws;
    float* mstats = hacc + (size_t)NNODES * 64;
    float* nstats = mstats + 256;
    float* mss    = nstats + 128;
    float* nss    = mss + 256;
    int* flag     = (int*)(nss + 128);
    bf16* tsrc    = (bf16*)(flag + 4);
    bf16* tdst    = tsrc + (size_t)NNODES * C2;
    int* cnt      = (int*)(tdst + (size_t)NNODES * C2);
    int* off      = cnt + NNODES;
    int* cur      = off + NNODES + 1;
    int* bsum     = cur + NNODES;
    int* srcp     = bsum + 512;
    bf16* efp     = (bf16*)((((uintptr_t)(srcp + NEDGES)) + 15) & ~(uintptr_t)15);
    uint4* Wep4   = (uint4*)(efp + (size_t)NEDGES * EFEAT);

    hipMemsetAsync(mstats, 0, 384 * sizeof(float), stream);
    hipMemsetAsync(cnt, 0, NNODES * sizeof(int), stream);
    k_detect<<<1, 256, 0, stream>>>((const uint32_t*)node, flag);
    // CSR build (atomic-free, gather-based edge passes)
    k_hist<<<2048, 256, 0, stream>>>(dst, cnt);
    k_scan1<<<SCAN_B, 256, 0, stream>>>(cnt, bsum);
    k_scan2<<<1, 512, 0, stream>>>(bsum);
    k_scan3<<<SCAN_B, 256, 0, stream>>>(cnt, bsum, off, cur);
    k_fill<<<2048, 256, 0, stream>>>(dst, src, ef, cur, srcp, (uint4*)efp, flag);
    k_prepw<<<1, 512, 0, stream>>>(We, Wep4, flag);
    k_tables<<<512, 256, 0, stream>>>(node, Wsrc, bsrc, Wdst, bdst, tsrc, tdst, flag);
    // MFMA edge pass 1: m-BN statistics
    k_edge_pass<true><<<2048, 256, 0, stream>>>(
        (const uint4*)efp, srcp, Wep4, be,
        (const uint32_t*)tsrc, (const uint32_t*)tdst,
        mss, off, hacc, mstats, flag);
    k_fin_m<<<1, 128, 0, stream>>>(mstats, gm, bm, mss, flag);
    // MFMA edge pass 2: gate + aggregate + fused n-BN statistics
    k_edge_pass<false><<<2048, 256, 0, stream>>>(
        (const uint4*)efp, srcp, Wep4, be,
        (const uint32_t*)tsrc, (const uint32_t*)tdst,
        mss, off, hacc, nstats, flag);
    k_fin_n<<<1, 64, 0, stream>>>(nstats, gn, bn, nss, flag);
    k_out<<<1024, 256, 0, stream>>>(node, hacc, nss, d_out, flag);
}